// Round 2
// baseline (7808.119 us; speedup 1.0000x reference)
//
#include <hip/hip_runtime.h>
#include <math.h>

#define BB 128
#define CC 23
#define TT 2000
#define NFFT 200
#define HOP 100
#define NFREQ 101
#define FTW 19
#define EMB 256
#define HEADS 8
#define DH 32
#define FFD 1024
#define DEPTH 4
#define SS (CC*FTW)          // 437
#define NROWS (BB*SS)        // 55936
#define ROWT 16              // rows per GEMM tile

// ---------------- tables: DFT cos/sin + positional encoding ----------------
__global__ __launch_bounds__(256) void k_init(float* cosT, float* sinT, float* pe) {
    int i = blockIdx.x * 256 + threadIdx.x;
    if (i < NFFT * NFREQ) {
        int n = i / NFREQ, k = i % NFREQ;
        int kn = (k * n) % NFFT;
        float th = 6.283185307179586f * (float)kn / (float)NFFT;
        cosT[i] = cosf(th);
        sinT[i] = sinf(th);
    }
    if (i < FTW * (EMB / 2)) {
        int t = i / (EMB / 2), j = i % (EMB / 2);
        float dv = expf((-9.210340371976184f / (float)EMB) * (float)(2 * j));
        float a = (float)t * dv;
        pe[t * EMB + 2 * j]     = sinf(a);
        pe[t * EMB + 2 * j + 1] = cosf(a);
    }
}

// ---------------- STFT magnitude (clean y=0, masked y=1) ----------------
// mask is int32 (bool -> int per harness convention)
__global__ __launch_bounds__(128) void k_stft(const float* __restrict__ x,
                                              const int* __restrict__ mask,
                                              const float* __restrict__ cosT,
                                              const float* __restrict__ sinT,
                                              float* __restrict__ specc,
                                              float* __restrict__ specm) {
    int bc = blockIdx.x;
    int masked = blockIdx.y;
    __shared__ float sig[TT];
    const float* xs = x + (size_t)bc * TT;
    const int* ms = mask + (size_t)bc * TT;
    for (int i = threadIdx.x; i < TT; i += 128) {
        float v = xs[i];
        if (masked && ms[i]) v = 0.f;
        sig[i] = v;
    }
    __syncthreads();
    int k = threadIdx.x;
    if (k >= NFREQ) return;
    float re[FTW], im[FTW];
#pragma unroll
    for (int f = 0; f < FTW; f++) { re[f] = 0.f; im[f] = 0.f; }
    for (int n = 0; n < NFFT; n++) {
        float c = cosT[n * NFREQ + k];
        float s = sinT[n * NFREQ + k];
#pragma unroll
        for (int f = 0; f < FTW; f++) {
            float v = sig[f * HOP + n];
            re[f] += v * c;
            im[f] += v * s;
        }
    }
    float* out = masked ? specm : specc;
#pragma unroll
    for (int f = 0; f < FTW; f++) {
        out[((size_t)bc * FTW + f) * NFREQ + k] = sqrtf(re[f] * re[f] + im[f] * im[f]);
    }
}

// ---------------- spec @ W_proj + b + tok + pe ----------------
__global__ __launch_bounds__(256) void k_proj(const float* __restrict__ spec,
                                              const float* __restrict__ Wp,
                                              const float* __restrict__ bp,
                                              const float* __restrict__ tok,
                                              const int* __restrict__ offp,
                                              const float* __restrict__ pe,
                                              float* __restrict__ out) {
    int r0 = blockIdx.x * ROWT;
    __shared__ float sp[ROWT][NFREQ];
    for (int i = threadIdx.x; i < ROWT * NFREQ; i += 256) {
        int r = i / NFREQ, kk = i % NFREQ;
        sp[r][kk] = spec[(size_t)(r0 + r) * NFREQ + kk];
    }
    __syncthreads();
    int j = threadIdx.x;
    float acc[ROWT];
#pragma unroll
    for (int r = 0; r < ROWT; r++) acc[r] = 0.f;
    for (int kk = 0; kk < NFREQ; kk++) {
        float w = Wp[kk * EMB + j];
#pragma unroll
        for (int r = 0; r < ROWT; r++) acc[r] += sp[r][kk] * w;
    }
    int off = *offp;
    float bj = bp[j];
#pragma unroll
    for (int r = 0; r < ROWT; r++) {
        int g = r0 + r;
        int c = (g / FTW) % CC;
        int f = g % FTW;
        out[(size_t)g * EMB + j] = acc[r] + bj + tok[(c + off) * EMB + j] + pe[f * EMB + j];
    }
}

// ---------------- layernorm (one row per block) ----------------
__global__ __launch_bounds__(256) void k_ln(const float* __restrict__ h,
                                            const float* __restrict__ g,
                                            const float* __restrict__ b,
                                            float* __restrict__ out) {
    int row = blockIdx.x;
    int j = threadIdx.x;
    float v = h[(size_t)row * EMB + j];
    float s1 = v, s2 = v * v;
#pragma unroll
    for (int m = 1; m < 64; m <<= 1) {
        s1 += __shfl_xor(s1, m);
        s2 += __shfl_xor(s2, m);
    }
    __shared__ float r1[4], r2[4];
    int w = j >> 6;
    if ((j & 63) == 0) { r1[w] = s1; r2[w] = s2; }
    __syncthreads();
    s1 = r1[0] + r1[1] + r1[2] + r1[3];
    s2 = r2[0] + r2[1] + r2[2] + r2[3];
    float mu = s1 * (1.f / EMB);
    float var = s2 * (1.f / EMB) - mu * mu;
    float rstd = rsqrtf(var + 1e-5f);
    out[(size_t)row * EMB + j] = (v - mu) * rstd * g[j] + b[j];
}

// ---------------- QKV GEMMs + q-softmax epilogue ----------------
__global__ __launch_bounds__(256) void k_qkv(const float* __restrict__ hn,
                                             const float* __restrict__ Wq,
                                             const float* __restrict__ Wk,
                                             const float* __restrict__ Wv,
                                             float* __restrict__ qb,
                                             float* __restrict__ kb,
                                             float* __restrict__ vb) {
    int r0 = blockIdx.x * ROWT;
    __shared__ float a[ROWT][EMB];
    for (int i = threadIdx.x; i < ROWT * EMB; i += 256) a[i >> 8][i & 255] = hn[(size_t)r0 * EMB + i];
    __syncthreads();
    int j = threadIdx.x;
    float aq[ROWT], ak[ROWT], av[ROWT];
#pragma unroll
    for (int r = 0; r < ROWT; r++) { aq[r] = 0.f; ak[r] = 0.f; av[r] = 0.f; }
    for (int kk = 0; kk < EMB; kk++) {
        float wq = Wq[kk * EMB + j];
        float wk = Wk[kk * EMB + j];
        float wv = Wv[kk * EMB + j];
#pragma unroll
        for (int r = 0; r < ROWT; r++) {
            float xv = a[r][kk];
            aq[r] += xv * wq;
            ak[r] += xv * wk;
            av[r] += xv * wv;
        }
    }
    const float scale = 0.17677669529663687f;  // 1/sqrt(32)
#pragma unroll
    for (int r = 0; r < ROWT; r++) {
        float xv = aq[r];
        float mx = xv;
#pragma unroll
        for (int m = 1; m < 32; m <<= 1) mx = fmaxf(mx, __shfl_xor(mx, m));
        float e = expf(xv - mx);
        float sm = e;
#pragma unroll
        for (int m = 1; m < 32; m <<= 1) sm += __shfl_xor(sm, m);
        aq[r] = e / sm * scale;
    }
#pragma unroll
    for (int r = 0; r < ROWT; r++) {
        size_t o = (size_t)(r0 + r) * EMB + j;
        qb[o] = aq[r];
        kb[o] = ak[r];
        vb[o] = av[r];
    }
}

// ---------------- k-softmax (over S) + ctx = k^T v per (b,h) ----------------
__global__ __launch_bounds__(256) void k_kctx(const float* __restrict__ kb,
                                              const float* __restrict__ vb,
                                              float* __restrict__ ctx) {
    int b = blockIdx.x >> 3, h = blockIdx.x & 7;
    int d = threadIdx.x & 31, g = threadIdx.x >> 5;  // g in [0,8)
    size_t colbase = (size_t)b * SS * EMB + h * DH;
    __shared__ float red[8][32];
    __shared__ float kmax[32], krs[32];
    float mx = -1e30f;
    for (int s = g; s < SS; s += 8) mx = fmaxf(mx, kb[colbase + (size_t)s * EMB + d]);
    red[g][d] = mx;
    __syncthreads();
    if (threadIdx.x < 32) {
        mx = red[0][d];
        for (int i = 1; i < 8; i++) mx = fmaxf(mx, red[i][d]);
        kmax[d] = mx;
    }
    __syncthreads();
    mx = kmax[d];
    float sm = 0.f;
    for (int s = g; s < SS; s += 8) sm += expf(kb[colbase + (size_t)s * EMB + d] - mx);
    __syncthreads();
    red[g][d] = sm;
    __syncthreads();
    if (threadIdx.x < 32) {
        sm = 0.f;
        for (int i = 0; i < 8; i++) sm += red[i][d];
        krs[d] = 1.f / sm;
    }
    __syncthreads();
    // phase 2: ctx[d][e] accumulate
    int e = threadIdx.x & 31, db = threadIdx.x >> 5;
    float acc[4] = {0.f, 0.f, 0.f, 0.f};
    __shared__ float ksm[8][32], vls[8][32];
    float kmd = kmax[d], krd = krs[d];
    for (int s0 = 0; s0 < SS; s0 += 8) {
        int s = s0 + g;
        float kvv = 0.f, vvv = 0.f;
        if (s < SS) {
            kvv = expf(kb[colbase + (size_t)s * EMB + d] - kmd) * krd;
            vvv = vb[colbase + (size_t)s * EMB + d];
        }
        __syncthreads();
        ksm[g][d] = kvv;
        vls[g][d] = vvv;
        __syncthreads();
#pragma unroll
        for (int ssx = 0; ssx < 8; ssx++) {
            float vv = vls[ssx][e];
#pragma unroll
            for (int i = 0; i < 4; i++) acc[i] += ksm[ssx][db * 4 + i] * vv;
        }
    }
#pragma unroll
    for (int i = 0; i < 4; i++)
        ctx[((size_t)b * HEADS + h) * DH * DH + (db * 4 + i) * 32 + e] = acc[i];
}

// ---------------- attn = q@ctx, then h += attn@Wo ----------------
__global__ __launch_bounds__(256) void k_attn_o(const float* __restrict__ qb,
                                                const float* __restrict__ ctx,
                                                const float* __restrict__ Wo,
                                                float* __restrict__ h) {
    int b = blockIdx.x;
    int r0 = blockIdx.y * ROWT;
    __shared__ float ctxs[HEADS * DH * DH];  // 8192 floats
    __shared__ float qs[ROWT][EMB];
    __shared__ float at[ROWT][EMB];
    for (int i = threadIdx.x; i < HEADS * DH * DH; i += 256) ctxs[i] = ctx[(size_t)b * HEADS * DH * DH + i];
    for (int i = threadIdx.x; i < ROWT * EMB; i += 256) {
        int r = i >> 8, c = i & 255;
        int s = r0 + r;
        qs[r][c] = (s < SS) ? qb[((size_t)b * SS + s) * EMB + c] : 0.f;
    }
    __syncthreads();
    int j = threadIdx.x;
    int hh = j >> 5, e = j & 31;
#pragma unroll
    for (int r = 0; r < ROWT; r++) {
        float sum = 0.f;
#pragma unroll
        for (int dd = 0; dd < 32; dd++) sum += qs[r][hh * 32 + dd] * ctxs[hh * 1024 + dd * 32 + e];
        at[r][j] = sum;
    }
    __syncthreads();
    float acc[ROWT];
#pragma unroll
    for (int r = 0; r < ROWT; r++) acc[r] = 0.f;
    for (int kk = 0; kk < EMB; kk++) {
        float w = Wo[kk * EMB + j];
#pragma unroll
        for (int r = 0; r < ROWT; r++) acc[r] += at[r][kk] * w;
    }
#pragma unroll
    for (int r = 0; r < ROWT; r++) {
        int s = r0 + r;
        if (s < SS) h[((size_t)b * SS + s) * EMB + j] += acc[r];
    }
}

// ---------------- fused FFN: h += gelu(hn@W1+b1)@W2 + b2 ----------------
// 16-row tile; 16x1024 intermediate kept in LDS (64KB) + 16x256 a-tile (16KB)
__global__ __launch_bounds__(256) void k_ffn(const float* __restrict__ hn,
                                             const float* __restrict__ W1,
                                             const float* __restrict__ b1,
                                             const float* __restrict__ W2,
                                             const float* __restrict__ b2,
                                             float* __restrict__ h) {
    int r0 = blockIdx.x * ROWT;
    __shared__ float a[ROWT][EMB];
    __shared__ float fl[ROWT][FFD];
    for (int i = threadIdx.x; i < ROWT * EMB; i += 256) a[i >> 8][i & 255] = hn[(size_t)r0 * EMB + i];
    __syncthreads();
    int j = threadIdx.x;
    {
        float acc[ROWT][4];
#pragma unroll
        for (int r = 0; r < ROWT; r++)
#pragma unroll
            for (int m = 0; m < 4; m++) acc[r][m] = 0.f;
        for (int kk = 0; kk < EMB; kk++) {
            float w0 = W1[(size_t)kk * FFD + j];
            float w1 = W1[(size_t)kk * FFD + j + 256];
            float w2 = W1[(size_t)kk * FFD + j + 512];
            float w3 = W1[(size_t)kk * FFD + j + 768];
#pragma unroll
            for (int r = 0; r < ROWT; r++) {
                float xv = a[r][kk];
                acc[r][0] += xv * w0;
                acc[r][1] += xv * w1;
                acc[r][2] += xv * w2;
                acc[r][3] += xv * w3;
            }
        }
#pragma unroll
        for (int m = 0; m < 4; m++) {
            float bb = b1[j + m * 256];
#pragma unroll
            for (int r = 0; r < ROWT; r++) {
                float xv = acc[r][m] + bb;
                float t = tanhf(0.7978845608028654f * (xv + 0.044715f * xv * xv * xv));
                fl[r][j + m * 256] = 0.5f * xv * (1.f + t);
            }
        }
    }
    __syncthreads();
    float acc2[ROWT];
#pragma unroll
    for (int r = 0; r < ROWT; r++) acc2[r] = 0.f;
    for (int kk = 0; kk < FFD; kk++) {
        float w = W2[(size_t)kk * EMB + j];
#pragma unroll
        for (int r = 0; r < ROWT; r++) acc2[r] += fl[r][kk] * w;
    }
    float bb = b2[j];
#pragma unroll
    for (int r = 0; r < ROWT; r++) h[(size_t)(r0 + r) * EMB + j] += acc2[r] + bb;
}

extern "C" void kernel_launch(void* const* d_in, const int* in_sizes, int n_in,
                              void* d_out, int out_size, void* d_ws, size_t ws_size,
                              hipStream_t stream) {
    const float* x    = (const float*)d_in[0];
    const int* mask   = (const int*)d_in[1];       // bool -> int32 per harness
    const int* offp   = (const int*)d_in[2];
    const float* Wp   = (const float*)d_in[3];
    const float* bp   = (const float*)d_in[4];
    const float* tok  = (const float*)d_in[5];
    const float* ln1g = (const float*)d_in[6];
    const float* ln1b = (const float*)d_in[7];
    const float* Wq   = (const float*)d_in[8];
    const float* Wk   = (const float*)d_in[9];
    const float* Wv   = (const float*)d_in[10];
    const float* Wo   = (const float*)d_in[11];
    const float* ln2g = (const float*)d_in[12];
    const float* ln2b = (const float*)d_in[13];
    const float* W1   = (const float*)d_in[14];
    const float* b1   = (const float*)d_in[15];
    const float* W2   = (const float*)d_in[16];
    const float* b2   = (const float*)d_in[17];

    float* out_embc = (float*)d_out;
    float* h = out_embc + (size_t)NROWS * EMB;  // second output, evolves in place

    // workspace layout (floats):
    //   [0, 46080)                      tables (cos/sin/pe)
    //   hn: 46080 + NROWS*EMB
    //   R (union):  specc+specm (2*5.65M)  ALIASED WITH  qb+kb+vb (3*14.3M)
    //   ctx: after R
    float* ws   = (float*)d_ws;
    float* cosT = ws;
    float* sinT = cosT + NFFT * NFREQ;
    float* pe   = sinT + NFFT * NFREQ;
    float* hn   = ws + 46080;
    float* Rb   = hn + (size_t)NROWS * EMB;
    float* specc = Rb;
    float* specm = specc + (size_t)BB * CC * FTW * NFREQ;
    float* qb = Rb;                          // aliases specs (disjoint lifetime)
    float* kb = qb + (size_t)NROWS * EMB;
    float* vb = kb + (size_t)NROWS * EMB;
    float* ctx = Rb + 3 * (size_t)NROWS * EMB;
    // total: 46080 + 4*NROWS*EMB + BB*HEADS*DH*DH floats ~= 233 MB

    k_init<<<79, 256, 0, stream>>>(cosT, sinT, pe);
    k_stft<<<dim3(BB * CC, 2), 128, 0, stream>>>(x, mask, cosT, sinT, specc, specm);
    k_proj<<<NROWS / ROWT, 256, 0, stream>>>(specc, Wp, bp, tok, offp, pe, out_embc);
    k_proj<<<NROWS / ROWT, 256, 0, stream>>>(specm, Wp, bp, tok, offp, pe, h);

    for (int l = 0; l < DEPTH; l++) {
        k_ln<<<NROWS, 256, 0, stream>>>(h, ln1g + l * EMB, ln1b + l * EMB, hn);
        k_qkv<<<NROWS / ROWT, 256, 0, stream>>>(hn, Wq + (size_t)l * EMB * EMB,
                                                Wk + (size_t)l * EMB * EMB,
                                                Wv + (size_t)l * EMB * EMB, qb, kb, vb);
        k_kctx<<<BB * HEADS, 256, 0, stream>>>(kb, vb, ctx);
        k_attn_o<<<dim3(BB, (SS + ROWT - 1) / ROWT), 256, 0, stream>>>(qb, ctx, Wo + (size_t)l * EMB * EMB, h);
        k_ln<<<NROWS, 256, 0, stream>>>(h, ln2g + l * EMB, ln2b + l * EMB, hn);
        k_ffn<<<NROWS / ROWT, 256, 0, stream>>>(hn, W1 + (size_t)l * EMB * FFD, b1 + (size_t)l * FFD,
                                                W2 + (size_t)l * FFD * EMB, b2 + (size_t)l * EMB, h);
    }
}

// Round 3
// 3807.878 us; speedup vs baseline: 2.0505x; 2.0505x over previous
//
#include <hip/hip_runtime.h>
#include <math.h>

#define BB 128
#define CC 23
#define TT 2000
#define NFFT 200
#define HOP 100
#define NFREQ 101
#define FTW 19
#define EMB 256
#define HEADS 8
#define DH 32
#define FFD 1024
#define DEPTH 4
#define SS (CC*FTW)          // 437
#define NROWS (BB*SS)        // 55936
#define ROWT 16

typedef __attribute__((ext_vector_type(8))) short bf16x8;
typedef __attribute__((ext_vector_type(4))) float f32x4;
#define MFMA16 __builtin_amdgcn_mfma_f32_16x16x32_bf16

__device__ inline unsigned short f2bf(float f) {
    unsigned u = __float_as_uint(f);
    unsigned r = (u + 0x7FFFu + ((u >> 16) & 1u)) >> 16;
    return (unsigned short)r;
}
__device__ inline bf16x8 ld_frag(const unsigned short* p) {  // 16B-aligned, LDS or global
    union { uint4 u; bf16x8 f; } v;
    v.u = *(const uint4*)p;
    return v.f;
}

// ---------------- tables ----------------
__global__ __launch_bounds__(256) void k_init(float* cosT, float* sinT, float* pe) {
    int i = blockIdx.x * 256 + threadIdx.x;
    if (i < NFFT * NFREQ) {
        int n = i / NFREQ, k = i % NFREQ;
        int kn = (k * n) % NFFT;
        float th = 6.283185307179586f * (float)kn / (float)NFFT;
        cosT[i] = cosf(th);
        sinT[i] = sinf(th);
    }
    if (i < FTW * (EMB / 2)) {
        int t = i / (EMB / 2), j = i % (EMB / 2);
        float dv = expf((-9.210340371976184f / (float)EMB) * (float)(2 * j));
        float a = (float)t * dv;
        pe[t * EMB + 2 * j]     = sinf(a);
        pe[t * EMB + 2 * j + 1] = cosf(a);
    }
}

// ---------------- fp32 [K][N] -> bf16 [N][K] transpose-convert ----------------
__global__ __launch_bounds__(256) void k_tr(const float* __restrict__ in, unsigned short* __restrict__ out,
                                            int K, int N, size_t inStride, size_t outStride) {
    __shared__ float t[32][33];
    int k0 = blockIdx.y * 32, n0 = blockIdx.x * 32;
    const float* ip = in + blockIdx.z * inStride;
    unsigned short* op = out + blockIdx.z * outStride;
    int tx = threadIdx.x & 31, ty = threadIdx.x >> 5;
#pragma unroll
    for (int i = 0; i < 32; i += 8)
        t[ty + i][tx] = ip[(size_t)(k0 + ty + i) * N + n0 + tx];
    __syncthreads();
#pragma unroll
    for (int i = 0; i < 32; i += 8)
        op[(size_t)(n0 + ty + i) * K + k0 + tx] = f2bf(t[tx][ty + i]);
}

// ---------------- STFT magnitude ----------------
__global__ __launch_bounds__(128) void k_stft(const float* __restrict__ x,
                                              const int* __restrict__ mask,
                                              const float* __restrict__ cosT,
                                              const float* __restrict__ sinT,
                                              float* __restrict__ specc,
                                              float* __restrict__ specm) {
    int bc = blockIdx.x;
    int masked = blockIdx.y;
    __shared__ float sig[TT];
    const float* xs = x + (size_t)bc * TT;
    const int* ms = mask + (size_t)bc * TT;
    for (int i = threadIdx.x; i < TT; i += 128) {
        float v = xs[i];
        if (masked && ms[i]) v = 0.f;
        sig[i] = v;
    }
    __syncthreads();
    int k = threadIdx.x;
    if (k >= NFREQ) return;
    float re[FTW], im[FTW];
#pragma unroll
    for (int f = 0; f < FTW; f++) { re[f] = 0.f; im[f] = 0.f; }
    for (int n = 0; n < NFFT; n++) {
        float c = cosT[n * NFREQ + k];
        float s = sinT[n * NFREQ + k];
#pragma unroll
        for (int f = 0; f < FTW; f++) {
            float v = sig[f * HOP + n];
            re[f] += v * c;
            im[f] += v * s;
        }
    }
    float* out = masked ? specm : specc;
#pragma unroll
    for (int f = 0; f < FTW; f++)
        out[((size_t)bc * FTW + f) * NFREQ + k] = sqrtf(re[f] * re[f] + im[f] * im[f]);
}

// ---------------- spec @ W_proj + b + tok + pe (fp32) ----------------
__global__ __launch_bounds__(256) void k_proj(const float* __restrict__ spec,
                                              const float* __restrict__ Wp,
                                              const float* __restrict__ bp,
                                              const float* __restrict__ tok,
                                              const int* __restrict__ offp,
                                              const float* __restrict__ pe,
                                              float* __restrict__ out) {
    int r0 = blockIdx.x * ROWT;
    __shared__ float sp[ROWT][NFREQ];
    for (int i = threadIdx.x; i < ROWT * NFREQ; i += 256) {
        int r = i / NFREQ, kk = i % NFREQ;
        sp[r][kk] = spec[(size_t)(r0 + r) * NFREQ + kk];
    }
    __syncthreads();
    int j = threadIdx.x;
    float acc[ROWT];
#pragma unroll
    for (int r = 0; r < ROWT; r++) acc[r] = 0.f;
    for (int kk = 0; kk < NFREQ; kk++) {
        float w = Wp[kk * EMB + j];
#pragma unroll
        for (int r = 0; r < ROWT; r++) acc[r] += sp[r][kk] * w;
    }
    int off = *offp;
    float bj = bp[j];
#pragma unroll
    for (int r = 0; r < ROWT; r++) {
        int g = r0 + r;
        int c = (g / FTW) % CC;
        int f = g % FTW;
        out[(size_t)g * EMB + j] = acc[r] + bj + tok[(c + off) * EMB + j] + pe[f * EMB + j];
    }
}

// ---------------- layernorm -> bf16 ----------------
__global__ __launch_bounds__(256) void k_ln(const float* __restrict__ h,
                                            const float* __restrict__ g,
                                            const float* __restrict__ b,
                                            unsigned short* __restrict__ out) {
    int row = blockIdx.x;
    int j = threadIdx.x;
    float v = h[(size_t)row * EMB + j];
    float s1 = v, s2 = v * v;
#pragma unroll
    for (int m = 1; m < 64; m <<= 1) {
        s1 += __shfl_xor(s1, m);
        s2 += __shfl_xor(s2, m);
    }
    __shared__ float r1[4], r2[4];
    int w = j >> 6;
    if ((j & 63) == 0) { r1[w] = s1; r2[w] = s2; }
    __syncthreads();
    s1 = r1[0] + r1[1] + r1[2] + r1[3];
    s2 = r2[0] + r2[1] + r2[2] + r2[3];
    float mu = s1 * (1.f / EMB);
    float var = s2 * (1.f / EMB) - mu * mu;
    float rstd = rsqrtf(var + 1e-5f);
    out[(size_t)row * EMB + j] = f2bf((v - mu) * rstd * g[j] + b[j]);
}

// ---------------- QKV MFMA: raw q,k,v fp32 out ----------------
__global__ __launch_bounds__(256, 4) void k_qkv(const unsigned short* __restrict__ hnb,
                                                const unsigned short* __restrict__ Wt,  // [768][256] bf16
                                                float* __restrict__ qb, float* __restrict__ kb,
                                                float* __restrict__ vb) {
    __shared__ unsigned short aT[64 * 264];
    int r0 = blockIdx.x * 64;
    for (int idx = threadIdx.x; idx < 64 * 32; idx += 256) {
        int row = idx >> 5, c8 = (idx & 31) << 3;
        *(uint4*)&aT[row * 264 + c8] = *(const uint4*)&hnb[(size_t)(r0 + row) * EMB + c8];
    }
    __syncthreads();
    int lane = threadIdx.x & 63, w = threadIdx.x >> 6;
    int m16 = lane & 15, q = lane >> 4;
    for (int gg = 0; gg < 3; gg++) {
        int c0 = w * 192 + gg * 64;
        f32x4 acc[4][4];
#pragma unroll
        for (int mt = 0; mt < 4; mt++)
#pragma unroll
            for (int nt = 0; nt < 4; nt++) acc[mt][nt] = (f32x4){0.f, 0.f, 0.f, 0.f};
        for (int kk = 0; kk < 8; kk++) {
            int k0 = kk * 32 + q * 8;
            bf16x8 af[4], bfr[4];
#pragma unroll
            for (int mt = 0; mt < 4; mt++) af[mt] = ld_frag(&aT[(mt * 16 + m16) * 264 + k0]);
#pragma unroll
            for (int nt = 0; nt < 4; nt++) bfr[nt] = ld_frag(&Wt[(size_t)(c0 + nt * 16 + m16) * EMB + k0]);
#pragma unroll
            for (int mt = 0; mt < 4; mt++)
#pragma unroll
                for (int nt = 0; nt < 4; nt++) acc[mt][nt] = MFMA16(af[mt], bfr[nt], acc[mt][nt], 0, 0, 0);
        }
#pragma unroll
        for (int nt = 0; nt < 4; nt++) {
            int cbase = c0 + nt * 16;
            float* outp = (cbase < 256) ? qb : (cbase < 512) ? kb : vb;
            int cc = (cbase & 255) + m16;
#pragma unroll
            for (int mt = 0; mt < 4; mt++)
#pragma unroll
                for (int r = 0; r < 4; r++)
                    outp[(size_t)(r0 + mt * 16 + q * 4 + r) * EMB + cc] = acc[mt][nt][r];
        }
    }
}

// ---------------- k-softmax + ctx^T = (softmax k)^T v, stored [b][h][e][d] ----------------
__global__ __launch_bounds__(256) void k_kctx(const float* __restrict__ kb,
                                              const float* __restrict__ vb,
                                              float* __restrict__ ctx) {
    int b = blockIdx.x >> 3, h = blockIdx.x & 7;
    int d = threadIdx.x & 31, g = threadIdx.x >> 5;
    size_t colbase = (size_t)b * SS * EMB + h * DH;
    __shared__ float red[8][32];
    __shared__ float kmax[32], krs[32];
    float mx = -1e30f;
    for (int s = g; s < SS; s += 8) mx = fmaxf(mx, kb[colbase + (size_t)s * EMB + d]);
    red[g][d] = mx;
    __syncthreads();
    if (threadIdx.x < 32) {
        mx = red[0][d];
        for (int i = 1; i < 8; i++) mx = fmaxf(mx, red[i][d]);
        kmax[d] = mx;
    }
    __syncthreads();
    mx = kmax[d];
    float sm = 0.f;
    for (int s = g; s < SS; s += 8) sm += __expf(kb[colbase + (size_t)s * EMB + d] - mx);
    __syncthreads();
    red[g][d] = sm;
    __syncthreads();
    if (threadIdx.x < 32) {
        sm = 0.f;
        for (int i = 0; i < 8; i++) sm += red[i][d];
        krs[d] = 1.f / sm;
    }
    __syncthreads();
    int e = threadIdx.x & 31, db = threadIdx.x >> 5;
    float acc[4] = {0.f, 0.f, 0.f, 0.f};
    __shared__ float ksm[8][32], vls[8][32];
    float kmd = kmax[d], krd = krs[d];
    for (int s0 = 0; s0 < SS; s0 += 8) {
        int s = s0 + g;
        float kvv = 0.f, vvv = 0.f;
        if (s < SS) {
            kvv = __expf(kb[colbase + (size_t)s * EMB + d] - kmd) * krd;
            vvv = vb[colbase + (size_t)s * EMB + d];
        }
        __syncthreads();
        ksm[g][d] = kvv;
        vls[g][d] = vvv;
        __syncthreads();
#pragma unroll
        for (int ssx = 0; ssx < 8; ssx++) {
            float vv = vls[ssx][e];
#pragma unroll
            for (int i = 0; i < 4; i++) acc[i] += ksm[ssx][db * 4 + i] * vv;
        }
    }
    // transposed store: ctx[b][h][e][d]
#pragma unroll
    for (int i = 0; i < 4; i++)
        ctx[((size_t)b * HEADS + h) * 1024 + e * 32 + (db * 4 + i)] = acc[i];
}

// ---------------- attn: q-softmax, at = q@blockdiag(ctx) via MFMA, h += at@Wo ----------------
__global__ __launch_bounds__(256, 4) void k_attn_o(const float* __restrict__ qb,
                                                   const float* __restrict__ ctxT,  // [b][h][32e][32d]
                                                   const unsigned short* __restrict__ WoT,  // [256][256] bf16
                                                   float* __restrict__ h) {
    int b = blockIdx.x, s0 = blockIdx.y * 16;
    __shared__ unsigned short qsmb[16 * 264];
    __shared__ unsigned short ctxb[8 * 32 * 48];
    __shared__ unsigned short atb[16 * 264];
    int j = threadIdx.x;
    for (int idx = j; idx < 8192; idx += 256) {
        int hh = idx >> 10, rem = idx & 1023, e = rem >> 5, d = rem & 31;
        ctxb[hh * (32 * 48) + e * 48 + d] = f2bf(ctxT[(size_t)b * 8192 + idx]);
    }
    int hh = j >> 5, e32 = j & 31;
    (void)e32;
    const float scale = 0.17677669529663687f;
    for (int r = 0; r < 16; r++) {
        int s = s0 + r; if (s > SS - 1) s = SS - 1;
        float v = qb[((size_t)b * SS + s) * EMB + j];
        float mxv = v;
#pragma unroll
        for (int m = 1; m < 32; m <<= 1) mxv = fmaxf(mxv, __shfl_xor(mxv, m));
        float ex = __expf(v - mxv);
        float sm = ex;
#pragma unroll
        for (int m = 1; m < 32; m <<= 1) sm += __shfl_xor(sm, m);
        qsmb[r * 264 + j] = f2bf(ex / sm * scale);
    }
    __syncthreads();
    int lane = threadIdx.x & 63, w = threadIdx.x >> 6;
    int m16 = lane & 15, q = lane >> 4;
    // per-head 16x32 @ 32x32 (one K=32 mfma per 16-col half)
#pragma unroll
    for (int hi = 0; hi < 2; hi++) {
        int head = w * 2 + hi;
        bf16x8 af = ld_frag(&qsmb[m16 * 264 + head * 32 + q * 8]);
#pragma unroll
        for (int half = 0; half < 2; half++) {
            bf16x8 bfr = ld_frag(&ctxb[head * (32 * 48) + (half * 16 + m16) * 48 + q * 8]);
            f32x4 acc = (f32x4){0.f, 0.f, 0.f, 0.f};
            acc = MFMA16(af, bfr, acc, 0, 0, 0);
#pragma unroll
            for (int r = 0; r < 4; r++)
                atb[(q * 4 + r) * 264 + head * 32 + half * 16 + m16] = f2bf(acc[r]);
        }
    }
    __syncthreads();
    // h += at @ Wo
    f32x4 acc2[4];
#pragma unroll
    for (int nt = 0; nt < 4; nt++) acc2[nt] = (f32x4){0.f, 0.f, 0.f, 0.f};
    for (int kk = 0; kk < 8; kk++) {
        int k0 = kk * 32 + q * 8;
        bf16x8 af = ld_frag(&atb[m16 * 264 + k0]);
#pragma unroll
        for (int nt = 0; nt < 4; nt++) {
            bf16x8 bfr = ld_frag(&WoT[(size_t)(w * 64 + nt * 16 + m16) * EMB + k0]);
            acc2[nt] = MFMA16(af, bfr, acc2[nt], 0, 0, 0);
        }
    }
#pragma unroll
    for (int nt = 0; nt < 4; nt++) {
        int c = w * 64 + nt * 16 + m16;
#pragma unroll
        for (int r = 0; r < 4; r++) {
            int s = s0 + q * 4 + r;
            if (s < SS) h[((size_t)b * SS + s) * EMB + c] += acc2[nt][r];
        }
    }
}

// ---------------- FFN1: f = gelu(hn @ W1 + b1), bf16 out ----------------
__global__ __launch_bounds__(256, 4) void k_ffn1(const unsigned short* __restrict__ hnb,
                                                 const unsigned short* __restrict__ W1T,  // [1024][256]
                                                 const float* __restrict__ b1,
                                                 unsigned short* __restrict__ f) {
    __shared__ unsigned short aT[64 * 264];
    int r0 = blockIdx.x * 64;
    for (int idx = threadIdx.x; idx < 64 * 32; idx += 256) {
        int row = idx >> 5, c8 = (idx & 31) << 3;
        *(uint4*)&aT[row * 264 + c8] = *(const uint4*)&hnb[(size_t)(r0 + row) * EMB + c8];
    }
    __syncthreads();
    int lane = threadIdx.x & 63, w = threadIdx.x >> 6;
    int m16 = lane & 15, q = lane >> 4;
    for (int gg = 0; gg < 4; gg++) {
        int c0 = w * 256 + gg * 64;
        f32x4 acc[4][4];
#pragma unroll
        for (int mt = 0; mt < 4; mt++)
#pragma unroll
            for (int nt = 0; nt < 4; nt++) acc[mt][nt] = (f32x4){0.f, 0.f, 0.f, 0.f};
        for (int kk = 0; kk < 8; kk++) {
            int k0 = kk * 32 + q * 8;
            bf16x8 af[4], bfr[4];
#pragma unroll
            for (int mt = 0; mt < 4; mt++) af[mt] = ld_frag(&aT[(mt * 16 + m16) * 264 + k0]);
#pragma unroll
            for (int nt = 0; nt < 4; nt++) bfr[nt] = ld_frag(&W1T[(size_t)(c0 + nt * 16 + m16) * EMB + k0]);
#pragma unroll
            for (int mt = 0; mt < 4; mt++)
#pragma unroll
                for (int nt = 0; nt < 4; nt++) acc[mt][nt] = MFMA16(af[mt], bfr[nt], acc[mt][nt], 0, 0, 0);
        }
#pragma unroll
        for (int nt = 0; nt < 4; nt++) {
            int c = c0 + nt * 16 + m16;
            float bias = b1[c];
#pragma unroll
            for (int mt = 0; mt < 4; mt++)
#pragma unroll
                for (int r = 0; r < 4; r++) {
                    float xv = acc[mt][nt][r] + bias;
                    float z = 0.7978845608028654f * (xv + 0.044715f * xv * xv * xv);
                    z = fminf(fmaxf(z, -15.f), 15.f);
                    float t = __expf(2.f * z);
                    float gl = 0.5f * xv * (1.f + (t - 1.f) / (t + 1.f));
                    f[(size_t)(r0 + mt * 16 + q * 4 + r) * FFD + c] = f2bf(gl);
                }
        }
    }
}

// ---------------- FFN2: h += f @ W2 + b2 ----------------
__global__ __launch_bounds__(256, 4) void k_ffn2(const unsigned short* __restrict__ f,
                                                 const unsigned short* __restrict__ W2T,  // [256][1024]
                                                 const float* __restrict__ b2,
                                                 float* __restrict__ h) {
    __shared__ unsigned short fT[64 * 136];
    int r0 = blockIdx.x * 64;
    int lane = threadIdx.x & 63, w = threadIdx.x >> 6;
    int m16 = lane & 15, q = lane >> 4;
    f32x4 acc[4][4];
#pragma unroll
    for (int mt = 0; mt < 4; mt++)
#pragma unroll
        for (int nt = 0; nt < 4; nt++) acc[mt][nt] = (f32x4){0.f, 0.f, 0.f, 0.f};
    for (int ch = 0; ch < 8; ch++) {
        __syncthreads();
        for (int idx = threadIdx.x; idx < 64 * 16; idx += 256) {
            int row = idx >> 4, c8 = (idx & 15) << 3;
            *(uint4*)&fT[row * 136 + c8] = *(const uint4*)&f[(size_t)(r0 + row) * FFD + ch * 128 + c8];
        }
        __syncthreads();
        for (int kk = 0; kk < 4; kk++) {
            int k0l = kk * 32 + q * 8;
            int kg = ch * 128 + k0l;
            bf16x8 af[4], bfr[4];
#pragma unroll
            for (int mt = 0; mt < 4; mt++) af[mt] = ld_frag(&fT[(mt * 16 + m16) * 136 + k0l]);
#pragma unroll
            for (int nt = 0; nt < 4; nt++) bfr[nt] = ld_frag(&W2T[(size_t)(w * 64 + nt * 16 + m16) * FFD + kg]);
#pragma unroll
            for (int mt = 0; mt < 4; mt++)
#pragma unroll
                for (int nt = 0; nt < 4; nt++) acc[mt][nt] = MFMA16(af[mt], bfr[nt], acc[mt][nt], 0, 0, 0);
        }
    }
#pragma unroll
    for (int nt = 0; nt < 4; nt++) {
        int c = w * 64 + nt * 16 + m16;
        float bias = b2[c];
#pragma unroll
        for (int mt = 0; mt < 4; mt++)
#pragma unroll
            for (int r = 0; r < 4; r++)
                h[(size_t)(r0 + mt * 16 + q * 4 + r) * EMB + c] += acc[mt][nt][r] + bias;
    }
}

extern "C" void kernel_launch(void* const* d_in, const int* in_sizes, int n_in,
                              void* d_out, int out_size, void* d_ws, size_t ws_size,
                              hipStream_t stream) {
    const float* x    = (const float*)d_in[0];
    const int* mask   = (const int*)d_in[1];
    const int* offp   = (const int*)d_in[2];
    const float* Wp   = (const float*)d_in[3];
    const float* bp   = (const float*)d_in[4];
    const float* tok  = (const float*)d_in[5];
    const float* ln1g = (const float*)d_in[6];
    const float* ln1b = (const float*)d_in[7];
    const float* Wq   = (const float*)d_in[8];
    const float* Wk   = (const float*)d_in[9];
    const float* Wv   = (const float*)d_in[10];
    const float* Wo   = (const float*)d_in[11];
    const float* ln2g = (const float*)d_in[12];
    const float* ln2b = (const float*)d_in[13];
    const float* W1   = (const float*)d_in[14];
    const float* b1   = (const float*)d_in[15];
    const float* W2   = (const float*)d_in[16];
    const float* b2   = (const float*)d_in[17];

    float* out_embc = (float*)d_out;
    float* h = out_embc + (size_t)NROWS * EMB;

    char* base = (char*)d_ws;
    float* cosT = (float*)base;
    float* sinT = cosT + NFFT * NFREQ;
    float* pe   = sinT + NFFT * NFREQ;
    size_t off = 46080ull * 4;                       // 184,320
    unsigned short* hnb = (unsigned short*)(base + off);
    off += (size_t)NROWS * EMB * 2;                  // +28.6 MB
    unsigned short* wT = (unsigned short*)(base + off);
    off += 3145728ull * 2;                           // +6.3 MB
    off = (off + 255) & ~255ull;
    float* Rb = (float*)(base + off);                // 172 MB union region
    float* specc = Rb;
    float* specm = specc + (size_t)BB * CC * FTW * NFREQ;
    float* qb = Rb;
    float* kb = qb + (size_t)NROWS * EMB;
    float* vb = kb + (size_t)NROWS * EMB;
    unsigned short* fbuf = (unsigned short*)Rb;      // aliases qkv (disjoint lifetime)
    off += 3ull * NROWS * EMB * 4;
    float* ctxT = (float*)(base + off);              // 4 MB

    unsigned short* WqkvT = wT;                      // [4][768*256]
    unsigned short* WoT   = wT + 786432;             // [4][256*256]
    unsigned short* W1T   = WoT + 262144;            // [4][1024*256]
    unsigned short* W2T   = W1T + 1048576;           // [4][256*1024]

    k_init<<<79, 256, 0, stream>>>(cosT, sinT, pe);
    k_tr<<<dim3(8, 8, 4), 256, 0, stream>>>(Wq, WqkvT + 0,      256, 256, 65536, 196608);
    k_tr<<<dim3(8, 8, 4), 256, 0, stream>>>(Wk, WqkvT + 65536,  256, 256, 65536, 196608);
    k_tr<<<dim3(8, 8, 4), 256, 0, stream>>>(Wv, WqkvT + 131072, 256, 256, 65536, 196608);
    k_tr<<<dim3(8, 8, 4), 256, 0, stream>>>(Wo, WoT, 256, 256, 65536, 65536);
    k_tr<<<dim3(32, 8, 4), 256, 0, stream>>>(W1, W1T, 256, 1024, 262144, 262144);
    k_tr<<<dim3(8, 32, 4), 256, 0, stream>>>(W2, W2T, 1024, 256, 262144, 262144);

    k_stft<<<dim3(BB * CC, 2), 128, 0, stream>>>(x, mask, cosT, sinT, specc, specm);
    k_proj<<<NROWS / ROWT, 256, 0, stream>>>(specc, Wp, bp, tok, offp, pe, out_embc);
    k_proj<<<NROWS / ROWT, 256, 0, stream>>>(specm, Wp, bp, tok, offp, pe, h);

    for (int l = 0; l < DEPTH; l++) {
        k_ln<<<NROWS, 256, 0, stream>>>(h, ln1g + l * EMB, ln1b + l * EMB, hnb);
        k_qkv<<<NROWS / 64, 256, 0, stream>>>(hnb, WqkvT + (size_t)l * 196608, qb, kb, vb);
        k_kctx<<<BB * HEADS, 256, 0, stream>>>(kb, vb, ctxT);
        k_attn_o<<<dim3(BB, (SS + 15) / 16), 256, 0, stream>>>(qb, ctxT, WoT + (size_t)l * 65536, h);
        k_ln<<<NROWS, 256, 0, stream>>>(h, ln2g + l * EMB, ln2b + l * EMB, hnb);
        k_ffn1<<<NROWS / 64, 256, 0, stream>>>(hnb, W1T + (size_t)l * 262144, b1 + (size_t)l * FFD, fbuf);
        k_ffn2<<<NROWS / 64, 256, 0, stream>>>(fbuf, W2T + (size_t)l * 262144, b2 + (size_t)l * EMB, h);
    }
}

// Round 4
// 2389.282 us; speedup vs baseline: 3.2680x; 1.5937x over previous
//
#include <hip/hip_runtime.h>
#include <math.h>

#define BB 128
#define CC 23
#define TT 2000
#define NFFT 200
#define HOP 100
#define NFREQ 101
#define FTW 19
#define EMB 256
#define HEADS 8
#define DH 32
#define FFD 1024
#define DEPTH 4
#define SS (CC*FTW)          // 437
#define NROWS (BB*SS)        // 55936
#define ROWT 16

typedef __attribute__((ext_vector_type(8))) short bf16x8;
typedef __attribute__((ext_vector_type(4))) float f32x4;
#define MFMA16 __builtin_amdgcn_mfma_f32_16x16x32_bf16

__device__ inline unsigned short f2bf(float f) {
    unsigned u = __float_as_uint(f);
    unsigned r = (u + 0x7FFFu + ((u >> 16) & 1u)) >> 16;
    return (unsigned short)r;
}
__device__ inline float bf2f(unsigned short s) {
    return __uint_as_float(((unsigned)s) << 16);
}
__device__ inline bf16x8 ld_frag(const unsigned short* p) {
    union { uint4 u; bf16x8 f; } v;
    v.u = *(const uint4*)p;
    return v.f;
}

// ---------------- tables: posenc ----------------
__global__ __launch_bounds__(256) void k_init(float* pe) {
    int i = blockIdx.x * 256 + threadIdx.x;
    if (i < FTW * (EMB / 2)) {
        int t = i / (EMB / 2), j = i % (EMB / 2);
        float dv = expf((-9.210340371976184f / (float)EMB) * (float)(2 * j));
        float a = (float)t * dv;
        pe[t * EMB + 2 * j]     = sinf(a);
        pe[t * EMB + 2 * j + 1] = cosf(a);
    }
}

// ---------------- DFT basis, B^T layout [256 n][224 k], cos/sin 16-blocks interleaved ----------------
// n-block 2t   = cos for freqs t*16..t*16+15
// n-block 2t+1 = sin for same freqs
__global__ __launch_bounds__(256) void k_binit(unsigned short* Bt) {
    int i = blockIdx.x * 256 + threadIdx.x;
    if (i >= 256 * 224) return;
    int n = i / 224, k = i - (i / 224) * 224;
    int fq = ((n >> 5) << 4) + (n & 15);
    int kind = (n >> 4) & 1;
    float v = 0.f;
    if (k < 200 && fq < 101) {
        int kn = (fq * k) % 200;
        float th = 6.283185307179586f * (float)kn / 200.f;
        v = kind ? sinf(th) : cosf(th);
    }
    Bt[n * 224 + k] = f2bf(v);
}

// ---------------- fp32 [K][N] -> bf16 [N][K] transpose-convert ----------------
__global__ __launch_bounds__(256) void k_tr(const float* __restrict__ in, unsigned short* __restrict__ out,
                                            int K, int N, size_t inStride, size_t outStride) {
    __shared__ float t[32][33];
    int k0 = blockIdx.y * 32, n0 = blockIdx.x * 32;
    const float* ip = in + blockIdx.z * inStride;
    unsigned short* op = out + blockIdx.z * outStride;
    int tx = threadIdx.x & 31, ty = threadIdx.x >> 5;
#pragma unroll
    for (int i = 0; i < 32; i += 8)
        t[ty + i][tx] = ip[(size_t)(k0 + ty + i) * N + n0 + tx];
    __syncthreads();
#pragma unroll
    for (int i = 0; i < 32; i += 8)
        op[(size_t)(n0 + ty + i) * K + k0 + tx] = f2bf(t[tx][ty + i]);
}

// ---------------- STFT magnitude via MFMA: frames @ DFT^T, fused |.| epilogue ----------------
__global__ __launch_bounds__(256, 2) void k_stft(const float* __restrict__ x,
                                                 const int* __restrict__ mask,
                                                 const unsigned short* __restrict__ Bt,
                                                 float* __restrict__ specc,
                                                 float* __restrict__ specm) {
    int masked = blockIdx.y;
    int r0 = blockIdx.x * 64;
    __shared__ unsigned short aT[64 * 232];
    for (int t = threadIdx.x; t < 64 * 29; t += 256) {
        int row = t / 29;
        int ch = t - row * 29;
        int col0 = ch * 8;
        union { uint4 u; unsigned short s[8]; } pk;
        if (col0 < 200) {
            int fr = r0 + row;
            int bc = fr / 19, f = fr - bc * 19;
            const float* src = x + (size_t)bc * TT + f * HOP + col0;
            float4 v0 = *(const float4*)src;
            float4 v1 = *(const float4*)(src + 4);
            if (masked) {
                const int* ms = mask + (size_t)bc * TT + f * HOP + col0;
                int4 m0 = *(const int4*)ms;
                int4 m1 = *(const int4*)(ms + 4);
                if (m0.x) v0.x = 0.f; if (m0.y) v0.y = 0.f; if (m0.z) v0.z = 0.f; if (m0.w) v0.w = 0.f;
                if (m1.x) v1.x = 0.f; if (m1.y) v1.y = 0.f; if (m1.z) v1.z = 0.f; if (m1.w) v1.w = 0.f;
            }
            pk.s[0] = f2bf(v0.x); pk.s[1] = f2bf(v0.y); pk.s[2] = f2bf(v0.z); pk.s[3] = f2bf(v0.w);
            pk.s[4] = f2bf(v1.x); pk.s[5] = f2bf(v1.y); pk.s[6] = f2bf(v1.z); pk.s[7] = f2bf(v1.w);
        } else {
            pk.u = (uint4){0, 0, 0, 0};
        }
        *(uint4*)&aT[row * 232 + col0] = pk.u;
    }
    __syncthreads();
    int lane = threadIdx.x & 63, w = threadIdx.x >> 6;
    int m16 = lane & 15, q = lane >> 4;
    f32x4 acc[4][4];
#pragma unroll
    for (int mt = 0; mt < 4; mt++)
#pragma unroll
        for (int nt = 0; nt < 4; nt++) acc[mt][nt] = (f32x4){0.f, 0.f, 0.f, 0.f};
    for (int kk = 0; kk < 7; kk++) {
        int k0 = kk * 32 + q * 8;
        bf16x8 af[4], bfr[4];
#pragma unroll
        for (int mt = 0; mt < 4; mt++) af[mt] = ld_frag(&aT[(mt * 16 + m16) * 232 + k0]);
#pragma unroll
        for (int nt = 0; nt < 4; nt++) bfr[nt] = ld_frag(&Bt[(w * 64 + nt * 16 + m16) * 224 + k0]);
#pragma unroll
        for (int mt = 0; mt < 4; mt++)
#pragma unroll
            for (int nt = 0; nt < 4; nt++) acc[mt][nt] = MFMA16(af[mt], bfr[nt], acc[mt][nt], 0, 0, 0);
    }
    float* out = masked ? specm : specc;
#pragma unroll
    for (int pt = 0; pt < 2; pt++) {
        int fq = w * 32 + pt * 16 + m16;
        if (fq < NFREQ) {
#pragma unroll
            for (int mt = 0; mt < 4; mt++)
#pragma unroll
                for (int r = 0; r < 4; r++) {
                    float re = acc[mt][pt * 2][r];
                    float im = acc[mt][pt * 2 + 1][r];
                    int row = mt * 16 + q * 4 + r;
                    out[(size_t)(r0 + row) * NFREQ + fq] = sqrtf(re * re + im * im);
                }
        }
    }
}

// ---------------- spec @ W_proj + b + tok + pe (fp32) ----------------
__global__ __launch_bounds__(256) void k_proj(const float* __restrict__ spec,
                                              const float* __restrict__ Wp,
                                              const float* __restrict__ bp,
                                              const float* __restrict__ tok,
                                              const int* __restrict__ offp,
                                              const float* __restrict__ pe,
                                              float* __restrict__ out) {
    int r0 = blockIdx.x * ROWT;
    __shared__ float sp[ROWT][NFREQ];
    for (int i = threadIdx.x; i < ROWT * NFREQ; i += 256) {
        int r = i / NFREQ, kk = i % NFREQ;
        sp[r][kk] = spec[(size_t)(r0 + r) * NFREQ + kk];
    }
    __syncthreads();
    int j = threadIdx.x;
    float acc[ROWT];
#pragma unroll
    for (int r = 0; r < ROWT; r++) acc[r] = 0.f;
    for (int kk = 0; kk < NFREQ; kk++) {
        float w = Wp[kk * EMB + j];
#pragma unroll
        for (int r = 0; r < ROWT; r++) acc[r] += sp[r][kk] * w;
    }
    int off = *offp;
    float bj = bp[j];
#pragma unroll
    for (int r = 0; r < ROWT; r++) {
        int g = r0 + r;
        int c = (g / FTW) % CC;
        int f = g % FTW;
        out[(size_t)g * EMB + j] = acc[r] + bj + tok[(c + off) * EMB + j] + pe[f * EMB + j];
    }
}

// ---- fused LN helper: 64 rows/block, 4 threads/row, writes bf16 into aT[row*264 + col] ----
__device__ inline void ln_stage(const float* __restrict__ h, int r0,
                                const float* __restrict__ g, const float* __restrict__ b,
                                unsigned short* aT) {
    int row = threadIdx.x >> 2, part = threadIdx.x & 3;
    const float* hr = h + (size_t)(r0 + row) * EMB + part * 64;
    float s1 = 0.f, s2 = 0.f;
#pragma unroll
    for (int i = 0; i < 16; i++) {
        float4 v = *(const float4*)(hr + i * 4);
        s1 += v.x + v.y + v.z + v.w;
        s2 += v.x * v.x + v.y * v.y + v.z * v.z + v.w * v.w;
    }
    s1 += __shfl_xor(s1, 1); s1 += __shfl_xor(s1, 2);
    s2 += __shfl_xor(s2, 1); s2 += __shfl_xor(s2, 2);
    float mu = s1 * (1.f / EMB);
    float var = s2 * (1.f / EMB) - mu * mu;
    float rstd = rsqrtf(var + 1e-5f);
#pragma unroll
    for (int i = 0; i < 8; i++) {
        int c0 = part * 64 + i * 8;
        float4 va = *(const float4*)(hr + i * 8);
        float4 vb = *(const float4*)(hr + i * 8 + 4);
        float4 ga = *(const float4*)(g + c0);
        float4 gb = *(const float4*)(g + c0 + 4);
        float4 ba = *(const float4*)(b + c0);
        float4 bb = *(const float4*)(b + c0 + 4);
        union { uint4 u; unsigned short s[8]; } pk;
        pk.s[0] = f2bf((va.x - mu) * rstd * ga.x + ba.x);
        pk.s[1] = f2bf((va.y - mu) * rstd * ga.y + ba.y);
        pk.s[2] = f2bf((va.z - mu) * rstd * ga.z + ba.z);
        pk.s[3] = f2bf((va.w - mu) * rstd * ga.w + ba.w);
        pk.s[4] = f2bf((vb.x - mu) * rstd * gb.x + bb.x);
        pk.s[5] = f2bf((vb.y - mu) * rstd * gb.y + bb.y);
        pk.s[6] = f2bf((vb.z - mu) * rstd * gb.z + bb.z);
        pk.s[7] = f2bf((vb.w - mu) * rstd * gb.w + bb.w);
        *(uint4*)&aT[row * 264 + c0] = pk.u;
    }
}

// ---------------- QKV: fused LN1 + MFMA, bf16 q/k/v out via LDS-staged full-line stores ----------------
__global__ __launch_bounds__(256, 2) void k_qkv(const float* __restrict__ h,
                                                const float* __restrict__ lng,
                                                const float* __restrict__ lnb,
                                                const unsigned short* __restrict__ Wt,  // [768][256]
                                                unsigned short* __restrict__ qb,
                                                unsigned short* __restrict__ kb,
                                                unsigned short* __restrict__ vb) {
    __shared__ unsigned short aT[64 * 264];
    __shared__ unsigned short ot[4][64 * 72];
    int r0 = blockIdx.x * 64;
    ln_stage(h, r0, lng, lnb, aT);
    __syncthreads();
    int lane = threadIdx.x & 63, w = threadIdx.x >> 6;
    int m16 = lane & 15, q = lane >> 4;
    for (int gg = 0; gg < 3; gg++) {
        int c0 = w * 192 + gg * 64;
        f32x4 acc[4][4];
#pragma unroll
        for (int mt = 0; mt < 4; mt++)
#pragma unroll
            for (int nt = 0; nt < 4; nt++) acc[mt][nt] = (f32x4){0.f, 0.f, 0.f, 0.f};
        for (int kk = 0; kk < 8; kk++) {
            int k0 = kk * 32 + q * 8;
            bf16x8 af[4], bfr[4];
#pragma unroll
            for (int mt = 0; mt < 4; mt++) af[mt] = ld_frag(&aT[(mt * 16 + m16) * 264 + k0]);
#pragma unroll
            for (int nt = 0; nt < 4; nt++) bfr[nt] = ld_frag(&Wt[(size_t)(c0 + nt * 16 + m16) * EMB + k0]);
#pragma unroll
            for (int mt = 0; mt < 4; mt++)
#pragma unroll
                for (int nt = 0; nt < 4; nt++) acc[mt][nt] = MFMA16(af[mt], bfr[nt], acc[mt][nt], 0, 0, 0);
        }
        // stage wave's 64x64 bf16 tile in LDS, then full-line global stores
#pragma unroll
        for (int nt = 0; nt < 4; nt++)
#pragma unroll
            for (int mt = 0; mt < 4; mt++)
#pragma unroll
                for (int r = 0; r < 4; r++)
                    ot[w][(mt * 16 + q * 4 + r) * 72 + nt * 16 + m16] = f2bf(acc[mt][nt][r]);
        unsigned short* dst;
        int cc0;
        if (c0 < 256)      { dst = qb; cc0 = c0; }
        else if (c0 < 512) { dst = kb; cc0 = c0 - 256; }
        else               { dst = vb; cc0 = c0 - 512; }
        for (int t = lane; t < 512; t += 64) {
            int row = t >> 3, c8 = (t & 7) * 8;
            *(uint4*)&dst[(size_t)(r0 + row) * EMB + cc0 + c8] = *(uint4*)&ot[w][row * 72 + c8];
        }
    }
}

// ---------------- k-softmax + ctx^T = (softmax k)^T v, stored [b][h][e][d], bf16 in ----------------
__global__ __launch_bounds__(256) void k_kctx(const unsigned short* __restrict__ kb,
                                              const unsigned short* __restrict__ vb,
                                              float* __restrict__ ctx) {
    int b = blockIdx.x >> 3, h = blockIdx.x & 7;
    int d = threadIdx.x & 31, g = threadIdx.x >> 5;
    size_t colbase = (size_t)b * SS * EMB + h * DH;
    __shared__ float red[8][32];
    __shared__ float kmax[32], krs[32];
    float mx = -1e30f;
    for (int s = g; s < SS; s += 8) mx = fmaxf(mx, bf2f(kb[colbase + (size_t)s * EMB + d]));
    red[g][d] = mx;
    __syncthreads();
    if (threadIdx.x < 32) {
        mx = red[0][d];
        for (int i = 1; i < 8; i++) mx = fmaxf(mx, red[i][d]);
        kmax[d] = mx;
    }
    __syncthreads();
    mx = kmax[d];
    float sm = 0.f;
    for (int s = g; s < SS; s += 8) sm += __expf(bf2f(kb[colbase + (size_t)s * EMB + d]) - mx);
    __syncthreads();
    red[g][d] = sm;
    __syncthreads();
    if (threadIdx.x < 32) {
        sm = 0.f;
        for (int i = 0; i < 8; i++) sm += red[i][d];
        krs[d] = 1.f / sm;
    }
    __syncthreads();
    int e = threadIdx.x & 31, db = threadIdx.x >> 5;
    float acc[4] = {0.f, 0.f, 0.f, 0.f};
    __shared__ float ksm[8][32], vls[8][32];
    float kmd = kmax[d], krd = krs[d];
    for (int s0 = 0; s0 < SS; s0 += 8) {
        int s = s0 + g;
        float kvv = 0.f, vvv = 0.f;
        if (s < SS) {
            kvv = __expf(bf2f(kb[colbase + (size_t)s * EMB + d]) - kmd) * krd;
            vvv = bf2f(vb[colbase + (size_t)s * EMB + d]);
        }
        __syncthreads();
        ksm[g][d] = kvv;
        vls[g][d] = vvv;
        __syncthreads();
#pragma unroll
        for (int ssx = 0; ssx < 8; ssx++) {
            float vv = vls[ssx][e];
#pragma unroll
            for (int i = 0; i < 4; i++) acc[i] += ksm[ssx][db * 4 + i] * vv;
        }
    }
#pragma unroll
    for (int i = 0; i < 4; i++)
        ctx[((size_t)b * HEADS + h) * 1024 + e * 32 + (db * 4 + i)] = acc[i];
}

// ---------------- attn: q-softmax (bf16 q), at = q@blockdiag(ctx) MFMA, h += at@Wo ----------------
__global__ __launch_bounds__(256, 4) void k_attn_o(const unsigned short* __restrict__ qb,
                                                   const float* __restrict__ ctxT,  // [b][h][32e][32d]
                                                   const unsigned short* __restrict__ WoT,
                                                   float* __restrict__ h) {
    int b = blockIdx.x, s0 = blockIdx.y * 16;
    __shared__ unsigned short qsmb[16 * 264];
    __shared__ unsigned short ctxb[8 * 32 * 48];
    __shared__ unsigned short atb[16 * 264];
    int j = threadIdx.x;
    for (int idx = j; idx < 8192; idx += 256) {
        int hh = idx >> 10, rem = idx & 1023, e = rem >> 5, d = rem & 31;
        ctxb[hh * (32 * 48) + e * 48 + d] = f2bf(ctxT[(size_t)b * 8192 + idx]);
    }
    const float scale = 0.17677669529663687f;
    for (int r = 0; r < 16; r++) {
        int s = s0 + r; if (s > SS - 1) s = SS - 1;
        float v = bf2f(qb[((size_t)b * SS + s) * EMB + j]);
        float mxv = v;
#pragma unroll
        for (int m = 1; m < 32; m <<= 1) mxv = fmaxf(mxv, __shfl_xor(mxv, m));
        float ex = __expf(v - mxv);
        float sm = ex;
#pragma unroll
        for (int m = 1; m < 32; m <<= 1) sm += __shfl_xor(sm, m);
        qsmb[r * 264 + j] = f2bf(ex / sm * scale);
    }
    __syncthreads();
    int lane = threadIdx.x & 63, w = threadIdx.x >> 6;
    int m16 = lane & 15, q = lane >> 4;
#pragma unroll
    for (int hi = 0; hi < 2; hi++) {
        int head = w * 2 + hi;
        bf16x8 af = ld_frag(&qsmb[m16 * 264 + head * 32 + q * 8]);
#pragma unroll
        for (int half = 0; half < 2; half++) {
            bf16x8 bfr = ld_frag(&ctxb[head * (32 * 48) + (half * 16 + m16) * 48 + q * 8]);
            f32x4 acc = (f32x4){0.f, 0.f, 0.f, 0.f};
            acc = MFMA16(af, bfr, acc, 0, 0, 0);
#pragma unroll
            for (int r = 0; r < 4; r++)
                atb[(q * 4 + r) * 264 + head * 32 + half * 16 + m16] = f2bf(acc[r]);
        }
    }
    __syncthreads();
    f32x4 acc2[4];
#pragma unroll
    for (int nt = 0; nt < 4; nt++) acc2[nt] = (f32x4){0.f, 0.f, 0.f, 0.f};
    for (int kk = 0; kk < 8; kk++) {
        int k0 = kk * 32 + q * 8;
        bf16x8 af = ld_frag(&atb[m16 * 264 + k0]);
#pragma unroll
        for (int nt = 0; nt < 4; nt++) {
            bf16x8 bfr = ld_frag(&WoT[(size_t)(w * 64 + nt * 16 + m16) * EMB + k0]);
            acc2[nt] = MFMA16(af, bfr, acc2[nt], 0, 0, 0);
        }
    }
#pragma unroll
    for (int nt = 0; nt < 4; nt++) {
        int c = w * 64 + nt * 16 + m16;
#pragma unroll
        for (int r = 0; r < 4; r++) {
            int s = s0 + q * 4 + r;
            if (s < SS) h[((size_t)b * SS + s) * EMB + c] += acc2[nt][r];
        }
    }
}

// ---------------- fused FFN: LN2 + h += gelu(hn@W1+b1)@W2 + b2, FF chunked through LDS ----------------
__global__ __launch_bounds__(256, 2) void k_ffn(const float* __restrict__ hin,
                                                const float* __restrict__ lng,
                                                const float* __restrict__ lnb,
                                                const unsigned short* __restrict__ W1T,  // [1024][256]
                                                const float* __restrict__ b1,
                                                const unsigned short* __restrict__ W2T,  // [256][1024]
                                                const float* __restrict__ b2,
                                                float* __restrict__ h) {
    __shared__ unsigned short aT[64 * 264];
    __shared__ unsigned short fch[64 * 264];
    int r0 = blockIdx.x * 64;
    ln_stage(hin, r0, lng, lnb, aT);
    __syncthreads();
    int lane = threadIdx.x & 63, w = threadIdx.x >> 6;
    int m16 = lane & 15, q = lane >> 4;
    f32x4 acc2[4][4];
#pragma unroll
    for (int mt = 0; mt < 4; mt++)
#pragma unroll
        for (int nt = 0; nt < 4; nt++) acc2[mt][nt] = (f32x4){0.f, 0.f, 0.f, 0.f};
    for (int ch = 0; ch < 4; ch++) {
        f32x4 accf[4][4];
#pragma unroll
        for (int mt = 0; mt < 4; mt++)
#pragma unroll
            for (int nt = 0; nt < 4; nt++) accf[mt][nt] = (f32x4){0.f, 0.f, 0.f, 0.f};
        for (int kk = 0; kk < 8; kk++) {
            int k0 = kk * 32 + q * 8;
            bf16x8 af[4], bfr[4];
#pragma unroll
            for (int mt = 0; mt < 4; mt++) af[mt] = ld_frag(&aT[(mt * 16 + m16) * 264 + k0]);
#pragma unroll
            for (int nt = 0; nt < 4; nt++)
                bfr[nt] = ld_frag(&W1T[(size_t)(ch * 256 + w * 64 + nt * 16 + m16) * EMB + k0]);
#pragma unroll
            for (int mt = 0; mt < 4; mt++)
#pragma unroll
                for (int nt = 0; nt < 4; nt++) accf[mt][nt] = MFMA16(af[mt], bfr[nt], accf[mt][nt], 0, 0, 0);
        }
        __syncthreads();  // prev chunk's second-GEMM reads of fch done
#pragma unroll
        for (int nt = 0; nt < 4; nt++) {
            int cl = w * 64 + nt * 16 + m16;
            float bias = b1[ch * 256 + cl];
#pragma unroll
            for (int mt = 0; mt < 4; mt++)
#pragma unroll
                for (int r = 0; r < 4; r++) {
                    float xv = accf[mt][nt][r] + bias;
                    float z = 0.7978845608028654f * (xv + 0.044715f * xv * xv * xv);
                    z = fminf(fmaxf(z, -15.f), 15.f);
                    float t = __expf(2.f * z);
                    float gl = 0.5f * xv * (1.f + (t - 1.f) / (t + 1.f));
                    fch[(mt * 16 + q * 4 + r) * 264 + cl] = f2bf(gl);
                }
        }
        __syncthreads();
        for (int kk = 0; kk < 8; kk++) {
            int k0 = kk * 32 + q * 8;
            bf16x8 af[4], bfr[4];
#pragma unroll
            for (int mt = 0; mt < 4; mt++) af[mt] = ld_frag(&fch[(mt * 16 + m16) * 264 + k0]);
#pragma unroll
            for (int nt = 0; nt < 4; nt++)
                bfr[nt] = ld_frag(&W2T[(size_t)(w * 64 + nt * 16 + m16) * FFD + ch * 256 + k0]);
#pragma unroll
            for (int mt = 0; mt < 4; mt++)
#pragma unroll
                for (int nt = 0; nt < 4; nt++) acc2[mt][nt] = MFMA16(af[mt], bfr[nt], acc2[mt][nt], 0, 0, 0);
        }
    }
#pragma unroll
    for (int nt = 0; nt < 4; nt++) {
        int c = w * 64 + nt * 16 + m16;
        float bias = b2[c];
#pragma unroll
        for (int mt = 0; mt < 4; mt++)
#pragma unroll
            for (int r = 0; r < 4; r++)
                h[(size_t)(r0 + mt * 16 + q * 4 + r) * EMB + c] += acc2[mt][nt][r] + bias;
    }
}

extern "C" void kernel_launch(void* const* d_in, const int* in_sizes, int n_in,
                              void* d_out, int out_size, void* d_ws, size_t ws_size,
                              hipStream_t stream) {
    const float* x    = (const float*)d_in[0];
    const int* mask   = (const int*)d_in[1];
    const int* offp   = (const int*)d_in[2];
    const float* Wp   = (const float*)d_in[3];
    const float* bp   = (const float*)d_in[4];
    const float* tok  = (const float*)d_in[5];
    const float* ln1g = (const float*)d_in[6];
    const float* ln1b = (const float*)d_in[7];
    const float* Wq   = (const float*)d_in[8];
    const float* Wk   = (const float*)d_in[9];
    const float* Wv   = (const float*)d_in[10];
    const float* Wo   = (const float*)d_in[11];
    const float* ln2g = (const float*)d_in[12];
    const float* ln2b = (const float*)d_in[13];
    const float* W1   = (const float*)d_in[14];
    const float* b1   = (const float*)d_in[15];
    const float* W2   = (const float*)d_in[16];
    const float* b2   = (const float*)d_in[17];

    float* out_embc = (float*)d_out;
    float* h = out_embc + (size_t)NROWS * EMB;

    // workspace (bytes):
    //   0        : pe fp32 [4864]                       (19456 B)
    //   19712    : Bt bf16 [256*224]                    (114688 B)
    //   134400   : wT bf16 [3145728]                    (6291456 B)
    //   6425856  : union { specc+specm fp32 (45 MB) | qb/kb/vb bf16 (86 MB) }
    //   92343552 : ctxT fp32 (4 MB)         total ~96.5 MB
    char* base = (char*)d_ws;
    float* pe = (float*)base;
    unsigned short* Bt = (unsigned short*)(base + 19712);
    unsigned short* wT = (unsigned short*)(base + 134400);
    unsigned short* qb = (unsigned short*)(base + 6425856);
    unsigned short* kb = qb + (size_t)NROWS * EMB;
    unsigned short* vb = kb + (size_t)NROWS * EMB;
    float* specc = (float*)qb;  // alias, disjoint lifetime
    float* specm = specc + (size_t)NROWS * NFREQ;
    float* ctxT = (float*)(base + 6425856 + 3ull * NROWS * EMB * 2);

    unsigned short* WqkvT = wT;                      // [4][768*256]
    unsigned short* WoT   = wT + 786432;             // [4][256*256]
    unsigned short* W1T   = WoT + 262144;            // [4][1024*256]
    unsigned short* W2T   = W1T + 1048576;           // [4][256*1024]

    k_init<<<10, 256, 0, stream>>>(pe);
    k_binit<<<224, 256, 0, stream>>>(Bt);
    k_tr<<<dim3(8, 8, 4), 256, 0, stream>>>(Wq, WqkvT + 0,      256, 256, 65536, 196608);
    k_tr<<<dim3(8, 8, 4), 256, 0, stream>>>(Wk, WqkvT + 65536,  256, 256, 65536, 196608);
    k_tr<<<dim3(8, 8, 4), 256, 0, stream>>>(Wv, WqkvT + 131072, 256, 256, 65536, 196608);
    k_tr<<<dim3(8, 8, 4), 256, 0, stream>>>(Wo, WoT, 256, 256, 65536, 65536);
    k_tr<<<dim3(32, 8, 4), 256, 0, stream>>>(W1, W1T, 256, 1024, 262144, 262144);
    k_tr<<<dim3(8, 32, 4), 256, 0, stream>>>(W2, W2T, 1024, 256, 262144, 262144);

    k_stft<<<dim3(NROWS / 64, 2), 256, 0, stream>>>(x, mask, Bt, specc, specm);
    k_proj<<<NROWS / ROWT, 256, 0, stream>>>(specc, Wp, bp, tok, offp, pe, out_embc);
    k_proj<<<NROWS / ROWT, 256, 0, stream>>>(specm, Wp, bp, tok, offp, pe, h);

    for (int l = 0; l < DEPTH; l++) {
        k_qkv<<<NROWS / 64, 256, 0, stream>>>(h, ln1g + l * EMB, ln1b + l * EMB,
                                              WqkvT + (size_t)l * 196608, qb, kb, vb);
        k_kctx<<<BB * HEADS, 256, 0, stream>>>(kb, vb, ctxT);
        k_attn_o<<<dim3(BB, (SS + 15) / 16), 256, 0, stream>>>(qb, ctxT, WoT + (size_t)l * 65536, h);
        k_ffn<<<NROWS / 64, 256, 0, stream>>>(h, ln2g + l * EMB, ln2b + l * EMB,
                                              W1T + (size_t)l * 262144, b1 + (size_t)l * FFD,
                                              W2T + (size_t)l * 262144, b2 + (size_t)l * EMB, h);
    }
}

// Round 5
// 2153.091 us; speedup vs baseline: 3.6265x; 1.1097x over previous
//
#include <hip/hip_runtime.h>
#include <math.h>

#define BB 128
#define CC 23
#define TT 2000
#define NFFT 200
#define HOP 100
#define NFREQ 101
#define FTW 19
#define EMB 256
#define HEADS 8
#define DH 32
#define FFD 1024
#define DEPTH 4
#define SS (CC*FTW)          // 437
#define NROWS (BB*SS)        // 55936
#define ROWT 16

typedef __attribute__((ext_vector_type(8))) short bf16x8;
typedef __attribute__((ext_vector_type(4))) float f32x4;
#define MFMA16 __builtin_amdgcn_mfma_f32_16x16x32_bf16

__device__ inline unsigned short f2bf(float f) {
    unsigned u = __float_as_uint(f);
    unsigned r = (u + 0x7FFFu + ((u >> 16) & 1u)) >> 16;
    return (unsigned short)r;
}
__device__ inline float bf2f(unsigned short s) {
    return __uint_as_float(((unsigned)s) << 16);
}
__device__ inline bf16x8 ld_frag(const unsigned short* p) {
    union { uint4 u; bf16x8 f; } v;
    v.u = *(const uint4*)p;
    return v.f;
}

// ---------------- tables: posenc ----------------
__global__ __launch_bounds__(256) void k_init(float* pe) {
    int i = blockIdx.x * 256 + threadIdx.x;
    if (i < FTW * (EMB / 2)) {
        int t = i / (EMB / 2), j = i % (EMB / 2);
        float dv = expf((-9.210340371976184f / (float)EMB) * (float)(2 * j));
        float a = (float)t * dv;
        pe[t * EMB + 2 * j]     = sinf(a);
        pe[t * EMB + 2 * j + 1] = cosf(a);
    }
}

// ---------------- DFT basis, B^T layout [256 n][224 k] ----------------
__global__ __launch_bounds__(256) void k_binit(unsigned short* Bt) {
    int i = blockIdx.x * 256 + threadIdx.x;
    if (i >= 256 * 224) return;
    int n = i / 224, k = i - (i / 224) * 224;
    int fq = ((n >> 5) << 4) + (n & 15);
    int kind = (n >> 4) & 1;
    float v = 0.f;
    if (k < 200 && fq < 101) {
        int kn = (fq * k) % 200;
        float th = 6.283185307179586f * (float)kn / 200.f;
        v = kind ? sinf(th) : cosf(th);
    }
    Bt[n * 224 + k] = f2bf(v);
}

// ---------------- fp32 [K][N] -> bf16 [N][K] transpose-convert ----------------
__global__ __launch_bounds__(256) void k_tr(const float* __restrict__ in, unsigned short* __restrict__ out,
                                            int K, int N, size_t inStride, size_t outStride) {
    __shared__ float t[32][33];
    int k0 = blockIdx.y * 32, n0 = blockIdx.x * 32;
    const float* ip = in + blockIdx.z * inStride;
    unsigned short* op = out + blockIdx.z * outStride;
    int tx = threadIdx.x & 31, ty = threadIdx.x >> 5;
#pragma unroll
    for (int i = 0; i < 32; i += 8)
        t[ty + i][tx] = ip[(size_t)(k0 + ty + i) * N + n0 + tx];
    __syncthreads();
#pragma unroll
    for (int i = 0; i < 32; i += 8)
        op[(size_t)(n0 + ty + i) * K + k0 + tx] = f2bf(t[tx][ty + i]);
}

// ---------------- STFT magnitude via MFMA ----------------
__global__ __launch_bounds__(256, 2) void k_stft(const float* __restrict__ x,
                                                 const int* __restrict__ mask,
                                                 const unsigned short* __restrict__ Bt,
                                                 float* __restrict__ specc,
                                                 float* __restrict__ specm) {
    int masked = blockIdx.y;
    int r0 = blockIdx.x * 64;
    __shared__ unsigned short aT[64 * 232];
    for (int t = threadIdx.x; t < 64 * 29; t += 256) {
        int row = t / 29;
        int ch = t - row * 29;
        int col0 = ch * 8;
        union { uint4 u; unsigned short s[8]; } pk;
        if (col0 < 200) {
            int fr = r0 + row;
            int bc = fr / 19, f = fr - bc * 19;
            const float* src = x + (size_t)bc * TT + f * HOP + col0;
            float4 v0 = *(const float4*)src;
            float4 v1 = *(const float4*)(src + 4);
            if (masked) {
                const int* ms = mask + (size_t)bc * TT + f * HOP + col0;
                int4 m0 = *(const int4*)ms;
                int4 m1 = *(const int4*)(ms + 4);
                if (m0.x) v0.x = 0.f; if (m0.y) v0.y = 0.f; if (m0.z) v0.z = 0.f; if (m0.w) v0.w = 0.f;
                if (m1.x) v1.x = 0.f; if (m1.y) v1.y = 0.f; if (m1.z) v1.z = 0.f; if (m1.w) v1.w = 0.f;
            }
            pk.s[0] = f2bf(v0.x); pk.s[1] = f2bf(v0.y); pk.s[2] = f2bf(v0.z); pk.s[3] = f2bf(v0.w);
            pk.s[4] = f2bf(v1.x); pk.s[5] = f2bf(v1.y); pk.s[6] = f2bf(v1.z); pk.s[7] = f2bf(v1.w);
        } else {
            pk.u = (uint4){0, 0, 0, 0};
        }
        *(uint4*)&aT[row * 232 + col0] = pk.u;
    }
    __syncthreads();
    int lane = threadIdx.x & 63, w = threadIdx.x >> 6;
    int m16 = lane & 15, q = lane >> 4;
    f32x4 acc[4][4];
#pragma unroll
    for (int mt = 0; mt < 4; mt++)
#pragma unroll
        for (int nt = 0; nt < 4; nt++) acc[mt][nt] = (f32x4){0.f, 0.f, 0.f, 0.f};
    for (int kk = 0; kk < 7; kk++) {
        int k0 = kk * 32 + q * 8;
        bf16x8 af[4], bfr[4];
#pragma unroll
        for (int mt = 0; mt < 4; mt++) af[mt] = ld_frag(&aT[(mt * 16 + m16) * 232 + k0]);
#pragma unroll
        for (int nt = 0; nt < 4; nt++) bfr[nt] = ld_frag(&Bt[(w * 64 + nt * 16 + m16) * 224 + k0]);
#pragma unroll
        for (int mt = 0; mt < 4; mt++)
#pragma unroll
            for (int nt = 0; nt < 4; nt++) acc[mt][nt] = MFMA16(af[mt], bfr[nt], acc[mt][nt], 0, 0, 0);
    }
    float* out = masked ? specm : specc;
#pragma unroll
    for (int pt = 0; pt < 2; pt++) {
        int fq = w * 32 + pt * 16 + m16;
        if (fq < NFREQ) {
#pragma unroll
            for (int mt = 0; mt < 4; mt++)
#pragma unroll
                for (int r = 0; r < 4; r++) {
                    float re = acc[mt][pt * 2][r];
                    float im = acc[mt][pt * 2 + 1][r];
                    int row = mt * 16 + q * 4 + r;
                    out[(size_t)(r0 + row) * NFREQ + fq] = sqrtf(re * re + im * im);
                }
        }
    }
}

// ---------------- spec @ W_proj + b + tok + pe (fp32) ----------------
__global__ __launch_bounds__(256) void k_proj(const float* __restrict__ spec,
                                              const float* __restrict__ Wp,
                                              const float* __restrict__ bp,
                                              const float* __restrict__ tok,
                                              const int* __restrict__ offp,
                                              const float* __restrict__ pe,
                                              float* __restrict__ out) {
    int r0 = blockIdx.x * ROWT;
    __shared__ float sp[ROWT][NFREQ];
    for (int i = threadIdx.x; i < ROWT * NFREQ; i += 256) {
        int r = i / NFREQ, kk = i % NFREQ;
        sp[r][kk] = spec[(size_t)(r0 + r) * NFREQ + kk];
    }
    __syncthreads();
    int j = threadIdx.x;
    float acc[ROWT];
#pragma unroll
    for (int r = 0; r < ROWT; r++) acc[r] = 0.f;
    for (int kk = 0; kk < NFREQ; kk++) {
        float w = Wp[kk * EMB + j];
#pragma unroll
        for (int r = 0; r < ROWT; r++) acc[r] += sp[r][kk] * w;
    }
    int off = *offp;
    float bj = bp[j];
#pragma unroll
    for (int r = 0; r < ROWT; r++) {
        int g = r0 + r;
        int c = (g / FTW) % CC;
        int f = g % FTW;
        out[(size_t)g * EMB + j] = acc[r] + bj + tok[(c + off) * EMB + j] + pe[f * EMB + j];
    }
}

// ---- fused LN helper: 64 rows/block, 512 threads (8/row), bf16 into aT[row*264+col] ----
__device__ inline void ln_stage8(const float* __restrict__ h, int r0,
                                 const float* __restrict__ g, const float* __restrict__ b,
                                 unsigned short* aT) {
    int row = threadIdx.x >> 3, part = threadIdx.x & 7;  // 32 cols each
    const float* hr = h + (size_t)(r0 + row) * EMB + part * 32;
    float s1 = 0.f, s2 = 0.f;
#pragma unroll
    for (int i = 0; i < 8; i++) {
        float4 v = *(const float4*)(hr + i * 4);
        s1 += v.x + v.y + v.z + v.w;
        s2 += v.x * v.x + v.y * v.y + v.z * v.z + v.w * v.w;
    }
    s1 += __shfl_xor(s1, 1); s1 += __shfl_xor(s1, 2); s1 += __shfl_xor(s1, 4);
    s2 += __shfl_xor(s2, 1); s2 += __shfl_xor(s2, 2); s2 += __shfl_xor(s2, 4);
    float mu = s1 * (1.f / EMB);
    float var = s2 * (1.f / EMB) - mu * mu;
    float rstd = rsqrtf(var + 1e-5f);
    const float* gp = g + part * 32;
    const float* bp = b + part * 32;
#pragma unroll
    for (int i = 0; i < 4; i++) {
        float4 va = *(const float4*)(hr + i * 8);
        float4 vb = *(const float4*)(hr + i * 8 + 4);
        float4 ga = *(const float4*)(gp + i * 8);
        float4 gb = *(const float4*)(gp + i * 8 + 4);
        float4 ba = *(const float4*)(bp + i * 8);
        float4 bb = *(const float4*)(bp + i * 8 + 4);
        union { uint4 u; unsigned short s[8]; } pk;
        pk.s[0] = f2bf((va.x - mu) * rstd * ga.x + ba.x);
        pk.s[1] = f2bf((va.y - mu) * rstd * ga.y + ba.y);
        pk.s[2] = f2bf((va.z - mu) * rstd * ga.z + ba.z);
        pk.s[3] = f2bf((va.w - mu) * rstd * ga.w + ba.w);
        pk.s[4] = f2bf((vb.x - mu) * rstd * gb.x + bb.x);
        pk.s[5] = f2bf((vb.y - mu) * rstd * gb.y + bb.y);
        pk.s[6] = f2bf((vb.z - mu) * rstd * gb.z + bb.z);
        pk.s[7] = f2bf((vb.w - mu) * rstd * gb.w + bb.w);
        *(uint4*)&aT[row * 264 + part * 32 + i * 8] = pk.u;
    }
}

// ---------------- QKV: fused LN1 + MFMA, 512 threads, reg-double-buffered weights ----------------
__global__ __launch_bounds__(512, 4) void k_qkv(const float* __restrict__ h,
                                                const float* __restrict__ lng,
                                                const float* __restrict__ lnb,
                                                const unsigned short* __restrict__ Wt,  // [768][256]
                                                unsigned short* __restrict__ qb,
                                                unsigned short* __restrict__ kb,
                                                unsigned short* __restrict__ vb) {
    __shared__ unsigned short aT[64 * 264];
    __shared__ unsigned short ob[64 * 264];
    int r0 = blockIdx.x * 64;
    ln_stage8(h, r0, lng, lnb, aT);
    __syncthreads();
    int lane = threadIdx.x & 63, w = threadIdx.x >> 6;  // w 0..7
    int m16 = lane & 15, q = lane >> 4;
    f32x4 acc[4][2];

    auto do_gemm = [&](int gg) {
        int cb = gg * 256 + w * 32;
#pragma unroll
        for (int mt = 0; mt < 4; mt++)
#pragma unroll
            for (int nt = 0; nt < 2; nt++) acc[mt][nt] = (f32x4){0.f, 0.f, 0.f, 0.f};
        bf16x8 bc0 = ld_frag(&Wt[(size_t)(cb + m16) * EMB + q * 8]);
        bf16x8 bc1 = ld_frag(&Wt[(size_t)(cb + 16 + m16) * EMB + q * 8]);
        for (int kk = 0; kk < 8; kk++) {
            int k0 = kk * 32 + q * 8;
            bf16x8 bn0, bn1;
            if (kk < 7) {
                bn0 = ld_frag(&Wt[(size_t)(cb + m16) * EMB + k0 + 32]);
                bn1 = ld_frag(&Wt[(size_t)(cb + 16 + m16) * EMB + k0 + 32]);
            }
            bf16x8 af[4];
#pragma unroll
            for (int mt = 0; mt < 4; mt++) af[mt] = ld_frag(&aT[(mt * 16 + m16) * 264 + k0]);
#pragma unroll
            for (int mt = 0; mt < 4; mt++) acc[mt][0] = MFMA16(af[mt], bc0, acc[mt][0], 0, 0, 0);
#pragma unroll
            for (int mt = 0; mt < 4; mt++) acc[mt][1] = MFMA16(af[mt], bc1, acc[mt][1], 0, 0, 0);
            bc0 = bn0; bc1 = bn1;
        }
    };

    do_gemm(0);
    for (int gg = 0; gg < 3; gg++) {
        __syncthreads();  // ob free
#pragma unroll
        for (int nt = 0; nt < 2; nt++)
#pragma unroll
            for (int mt = 0; mt < 4; mt++)
#pragma unroll
                for (int r = 0; r < 4; r++)
                    ob[(mt * 16 + q * 4 + r) * 264 + w * 32 + nt * 16 + m16] = f2bf(acc[mt][nt][r]);
        __syncthreads();  // ob ready
        unsigned short* dst = (gg == 0) ? qb : (gg == 1) ? kb : vb;
        for (int t = threadIdx.x; t < 2048; t += 512) {
            int row = t >> 5, c8 = (t & 31) * 8;
            *(uint4*)&dst[(size_t)(r0 + row) * EMB + c8] = *(uint4*)&ob[row * 264 + c8];
        }
        if (gg < 2) do_gemm(gg + 1);
    }
}

// ---------------- k-softmax + ctx^T, bf16 in ----------------
__global__ __launch_bounds__(256) void k_kctx(const unsigned short* __restrict__ kb,
                                              const unsigned short* __restrict__ vb,
                                              float* __restrict__ ctx) {
    int b = blockIdx.x >> 3, h = blockIdx.x & 7;
    int d = threadIdx.x & 31, g = threadIdx.x >> 5;
    size_t colbase = (size_t)b * SS * EMB + h * DH;
    __shared__ float red[8][32];
    __shared__ float kmax[32], krs[32];
    float mx = -1e30f;
    for (int s = g; s < SS; s += 8) mx = fmaxf(mx, bf2f(kb[colbase + (size_t)s * EMB + d]));
    red[g][d] = mx;
    __syncthreads();
    if (threadIdx.x < 32) {
        mx = red[0][d];
        for (int i = 1; i < 8; i++) mx = fmaxf(mx, red[i][d]);
        kmax[d] = mx;
    }
    __syncthreads();
    mx = kmax[d];
    float sm = 0.f;
    for (int s = g; s < SS; s += 8) sm += __expf(bf2f(kb[colbase + (size_t)s * EMB + d]) - mx);
    __syncthreads();
    red[g][d] = sm;
    __syncthreads();
    if (threadIdx.x < 32) {
        sm = 0.f;
        for (int i = 0; i < 8; i++) sm += red[i][d];
        krs[d] = 1.f / sm;
    }
    __syncthreads();
    int e = threadIdx.x & 31, db = threadIdx.x >> 5;
    float acc[4] = {0.f, 0.f, 0.f, 0.f};
    __shared__ float ksm[8][32], vls[8][32];
    float kmd = kmax[d], krd = krs[d];
    for (int s0 = 0; s0 < SS; s0 += 8) {
        int s = s0 + g;
        float kvv = 0.f, vvv = 0.f;
        if (s < SS) {
            kvv = __expf(bf2f(kb[colbase + (size_t)s * EMB + d]) - kmd) * krd;
            vvv = bf2f(vb[colbase + (size_t)s * EMB + d]);
        }
        __syncthreads();
        ksm[g][d] = kvv;
        vls[g][d] = vvv;
        __syncthreads();
#pragma unroll
        for (int ssx = 0; ssx < 8; ssx++) {
            float vv = vls[ssx][e];
#pragma unroll
            for (int i = 0; i < 4; i++) acc[i] += ksm[ssx][db * 4 + i] * vv;
        }
    }
#pragma unroll
    for (int i = 0; i < 4; i++)
        ctx[((size_t)b * HEADS + h) * 1024 + e * 32 + (db * 4 + i)] = acc[i];
}

// ---------------- attn: q-softmax + q@blockdiag(ctx) + h += at@Wo ----------------
__global__ __launch_bounds__(256, 4) void k_attn_o(const unsigned short* __restrict__ qb,
                                                   const float* __restrict__ ctxT,
                                                   const unsigned short* __restrict__ WoT,
                                                   float* __restrict__ h) {
    int b = blockIdx.x, s0 = blockIdx.y * 16;
    __shared__ unsigned short qsmb[16 * 264];
    __shared__ unsigned short ctxb[8 * 32 * 48];
    __shared__ unsigned short atb[16 * 264];
    int j = threadIdx.x;
    for (int idx = j; idx < 8192; idx += 256) {
        int hh = idx >> 10, rem = idx & 1023, e = rem >> 5, d = rem & 31;
        ctxb[hh * (32 * 48) + e * 48 + d] = f2bf(ctxT[(size_t)b * 8192 + idx]);
    }
    const float scale = 0.17677669529663687f;
    for (int r = 0; r < 16; r++) {
        int s = s0 + r; if (s > SS - 1) s = SS - 1;
        float v = bf2f(qb[((size_t)b * SS + s) * EMB + j]);
        float mxv = v;
#pragma unroll
        for (int m = 1; m < 32; m <<= 1) mxv = fmaxf(mxv, __shfl_xor(mxv, m));
        float ex = __expf(v - mxv);
        float sm = ex;
#pragma unroll
        for (int m = 1; m < 32; m <<= 1) sm += __shfl_xor(sm, m);
        qsmb[r * 264 + j] = f2bf(ex / sm * scale);
    }
    __syncthreads();
    int lane = threadIdx.x & 63, w = threadIdx.x >> 6;
    int m16 = lane & 15, q = lane >> 4;
#pragma unroll
    for (int hi = 0; hi < 2; hi++) {
        int head = w * 2 + hi;
        bf16x8 af = ld_frag(&qsmb[m16 * 264 + head * 32 + q * 8]);
#pragma unroll
        for (int half = 0; half < 2; half++) {
            bf16x8 bfr = ld_frag(&ctxb[head * (32 * 48) + (half * 16 + m16) * 48 + q * 8]);
            f32x4 acc = (f32x4){0.f, 0.f, 0.f, 0.f};
            acc = MFMA16(af, bfr, acc, 0, 0, 0);
#pragma unroll
            for (int r = 0; r < 4; r++)
                atb[(q * 4 + r) * 264 + head * 32 + half * 16 + m16] = f2bf(acc[r]);
        }
    }
    __syncthreads();
    f32x4 acc2[4];
#pragma unroll
    for (int nt = 0; nt < 4; nt++) acc2[nt] = (f32x4){0.f, 0.f, 0.f, 0.f};
    for (int kk = 0; kk < 8; kk++) {
        int k0 = kk * 32 + q * 8;
        bf16x8 af = ld_frag(&atb[m16 * 264 + k0]);
#pragma unroll
        for (int nt = 0; nt < 4; nt++) {
            bf16x8 bfr = ld_frag(&WoT[(size_t)(w * 64 + nt * 16 + m16) * EMB + k0]);
            acc2[nt] = MFMA16(af, bfr, acc2[nt], 0, 0, 0);
        }
    }
#pragma unroll
    for (int nt = 0; nt < 4; nt++) {
        int c = w * 64 + nt * 16 + m16;
#pragma unroll
        for (int r = 0; r < 4; r++) {
            int s = s0 + q * 4 + r;
            if (s < SS) h[((size_t)b * SS + s) * EMB + c] += acc2[nt][r];
        }
    }
}

// ---------------- fused FFN: 512 threads, interleaved read-phases, reg-dbuf weights ----------------
__global__ __launch_bounds__(512, 4) void k_ffn(const float* __restrict__ hin,
                                                const float* __restrict__ lng,
                                                const float* __restrict__ lnb,
                                                const unsigned short* __restrict__ W1T,  // [1024][256]
                                                const float* __restrict__ b1,
                                                const unsigned short* __restrict__ W2T,  // [256][1024]
                                                const float* __restrict__ b2,
                                                float* __restrict__ h) {
    __shared__ unsigned short aT[64 * 264];
    __shared__ unsigned short fch[64 * 264];
    int r0 = blockIdx.x * 64;
    ln_stage8(hin, r0, lng, lnb, aT);
    __syncthreads();
    int lane = threadIdx.x & 63, w = threadIdx.x >> 6;  // 8 waves
    int m16 = lane & 15, q = lane >> 4;
    f32x4 acc2[4][2];
#pragma unroll
    for (int mt = 0; mt < 4; mt++)
#pragma unroll
        for (int nt = 0; nt < 2; nt++) acc2[mt][nt] = (f32x4){0.f, 0.f, 0.f, 0.f};
    f32x4 accf[4][2];

    auto gemm1 = [&](int ch) {
        int cb = ch * 256 + w * 32;
#pragma unroll
        for (int mt = 0; mt < 4; mt++)
#pragma unroll
            for (int nt = 0; nt < 2; nt++) accf[mt][nt] = (f32x4){0.f, 0.f, 0.f, 0.f};
        bf16x8 bc0 = ld_frag(&W1T[(size_t)(cb + m16) * EMB + q * 8]);
        bf16x8 bc1 = ld_frag(&W1T[(size_t)(cb + 16 + m16) * EMB + q * 8]);
        for (int kk = 0; kk < 8; kk++) {
            int k0 = kk * 32 + q * 8;
            bf16x8 bn0, bn1;
            if (kk < 7) {
                bn0 = ld_frag(&W1T[(size_t)(cb + m16) * EMB + k0 + 32]);
                bn1 = ld_frag(&W1T[(size_t)(cb + 16 + m16) * EMB + k0 + 32]);
            }
            bf16x8 af[4];
#pragma unroll
            for (int mt = 0; mt < 4; mt++) af[mt] = ld_frag(&aT[(mt * 16 + m16) * 264 + k0]);
#pragma unroll
            for (int mt = 0; mt < 4; mt++) accf[mt][0] = MFMA16(af[mt], bc0, accf[mt][0], 0, 0, 0);
#pragma unroll
            for (int mt = 0; mt < 4; mt++) accf[mt][1] = MFMA16(af[mt], bc1, accf[mt][1], 0, 0, 0);
            bc0 = bn0; bc1 = bn1;
        }
    };

    gemm1(0);
    for (int ch = 0; ch < 4; ch++) {
        __syncthreads();  // fch free (prior gemm2 reads done)
#pragma unroll
        for (int nt = 0; nt < 2; nt++) {
            int cl = w * 32 + nt * 16 + m16;
            float bias = b1[ch * 256 + cl];
#pragma unroll
            for (int mt = 0; mt < 4; mt++)
#pragma unroll
                for (int r = 0; r < 4; r++) {
                    float xv = accf[mt][nt][r] + bias;
                    float z = 0.7978845608028654f * (xv + 0.044715f * xv * xv * xv);
                    z = fminf(fmaxf(z, -15.f), 15.f);
                    float t = __expf(2.f * z);
                    float gl = 0.5f * xv * (1.f + (t - 1.f) / (t + 1.f));
                    fch[(mt * 16 + q * 4 + r) * 264 + cl] = f2bf(gl);
                }
        }
        __syncthreads();  // fch ready
        // GEMM2(ch): K = ff-cols [ch*256, ch*256+256)
        {
            int rb = w * 32;  // output col base
            bf16x8 bc0 = ld_frag(&W2T[(size_t)(rb + m16) * FFD + ch * 256 + q * 8]);
            bf16x8 bc1 = ld_frag(&W2T[(size_t)(rb + 16 + m16) * FFD + ch * 256 + q * 8]);
            for (int kk = 0; kk < 8; kk++) {
                int k0 = kk * 32 + q * 8;
                bf16x8 bn0, bn1;
                if (kk < 7) {
                    bn0 = ld_frag(&W2T[(size_t)(rb + m16) * FFD + ch * 256 + k0 + 32]);
                    bn1 = ld_frag(&W2T[(size_t)(rb + 16 + m16) * FFD + ch * 256 + k0 + 32]);
                }
                bf16x8 af[4];
#pragma unroll
                for (int mt = 0; mt < 4; mt++) af[mt] = ld_frag(&fch[(mt * 16 + m16) * 264 + k0]);
#pragma unroll
                for (int mt = 0; mt < 4; mt++) acc2[mt][0] = MFMA16(af[mt], bc0, acc2[mt][0], 0, 0, 0);
#pragma unroll
                for (int mt = 0; mt < 4; mt++) acc2[mt][1] = MFMA16(af[mt], bc1, acc2[mt][1], 0, 0, 0);
                bc0 = bn0; bc1 = bn1;
            }
        }
        if (ch < 3) gemm1(ch + 1);
    }
#pragma unroll
    for (int nt = 0; nt < 2; nt++) {
        int c = w * 32 + nt * 16 + m16;
        float bias = b2[c];
#pragma unroll
        for (int mt = 0; mt < 4; mt++)
#pragma unroll
            for (int r = 0; r < 4; r++)
                h[(size_t)(r0 + mt * 16 + q * 4 + r) * EMB + c] += acc2[mt][nt][r] + bias;
    }
}

extern "C" void kernel_launch(void* const* d_in, const int* in_sizes, int n_in,
                              void* d_out, int out_size, void* d_ws, size_t ws_size,
                              hipStream_t stream) {
    const float* x    = (const float*)d_in[0];
    const int* mask   = (const int*)d_in[1];
    const int* offp   = (const int*)d_in[2];
    const float* Wp   = (const float*)d_in[3];
    const float* bp   = (const float*)d_in[4];
    const float* tok  = (const float*)d_in[5];
    const float* ln1g = (const float*)d_in[6];
    const float* ln1b = (const float*)d_in[7];
    const float* Wq   = (const float*)d_in[8];
    const float* Wk   = (const float*)d_in[9];
    const float* Wv   = (const float*)d_in[10];
    const float* Wo   = (const float*)d_in[11];
    const float* ln2g = (const float*)d_in[12];
    const float* ln2b = (const float*)d_in[13];
    const float* W1   = (const float*)d_in[14];
    const float* b1   = (const float*)d_in[15];
    const float* W2   = (const float*)d_in[16];
    const float* b2   = (const float*)d_in[17];

    float* out_embc = (float*)d_out;
    float* h = out_embc + (size_t)NROWS * EMB;

    char* base = (char*)d_ws;
    float* pe = (float*)base;
    unsigned short* Bt = (unsigned short*)(base + 19712);
    unsigned short* wT = (unsigned short*)(base + 134400);
    unsigned short* qb = (unsigned short*)(base + 6425856);
    unsigned short* kb = qb + (size_t)NROWS * EMB;
    unsigned short* vb = kb + (size_t)NROWS * EMB;
    float* specc = (float*)qb;  // alias, disjoint lifetime
    float* specm = specc + (size_t)NROWS * NFREQ;
    float* ctxT = (float*)(base + 6425856 + 3ull * NROWS * EMB * 2);

    unsigned short* WqkvT = wT;                      // [4][768*256]
    unsigned short* WoT   = wT + 786432;             // [4][256*256]
    unsigned short* W1T   = WoT + 262144;            // [4][1024*256]
    unsigned short* W2T   = W1T + 1048576;           // [4][256*1024]

    k_init<<<10, 256, 0, stream>>>(pe);
    k_binit<<<224, 256, 0, stream>>>(Bt);
    k_tr<<<dim3(8, 8, 4), 256, 0, stream>>>(Wq, WqkvT + 0,      256, 256, 65536, 196608);
    k_tr<<<dim3(8, 8, 4), 256, 0, stream>>>(Wk, WqkvT + 65536,  256, 256, 65536, 196608);
    k_tr<<<dim3(8, 8, 4), 256, 0, stream>>>(Wv, WqkvT + 131072, 256, 256, 65536, 196608);
    k_tr<<<dim3(8, 8, 4), 256, 0, stream>>>(Wo, WoT, 256, 256, 65536, 65536);
    k_tr<<<dim3(32, 8, 4), 256, 0, stream>>>(W1, W1T, 256, 1024, 262144, 262144);
    k_tr<<<dim3(8, 32, 4), 256, 0, stream>>>(W2, W2T, 1024, 256, 262144, 262144);

    k_stft<<<dim3(NROWS / 64, 2), 256, 0, stream>>>(x, mask, Bt, specc, specm);
    k_proj<<<NROWS / ROWT, 256, 0, stream>>>(specc, Wp, bp, tok, offp, pe, out_embc);
    k_proj<<<NROWS / ROWT, 256, 0, stream>>>(specm, Wp, bp, tok, offp, pe, h);

    for (int l = 0; l < DEPTH; l++) {
        k_qkv<<<NROWS / 64, 512, 0, stream>>>(h, ln1g + l * EMB, ln1b + l * EMB,
                                              WqkvT + (size_t)l * 196608, qb, kb, vb);
        k_kctx<<<BB * HEADS, 256, 0, stream>>>(kb, vb, ctxT);
        k_attn_o<<<dim3(BB, (SS + 15) / 16), 256, 0, stream>>>(qb, ctxT, WoT + (size_t)l * 65536, h);
        k_ffn<<<NROWS / 64, 512, 0, stream>>>(h, ln2g + l * EMB, ln2b + l * EMB,
                                              W1T + (size_t)l * 262144, b1 + (size_t)l * FFD,
                                              W2T + (size_t)l * 262144, b2 + (size_t)l * EMB, h);
    }
}